// Round 2
// baseline (1257.334 us; speedup 1.0000x reference)
//
#include <hip/hip_runtime.h>
#include <math.h>

// ---------------------------------------------------------------------------
// GraphSAGE (max aggr) x2 + LN + ReLU + MLP head + sigmoid.
// CSR build (atomics + scan) -> gather-max aggregation -> shuffle-GEMM linear
// layers with weights transposed in LDS. Intermediates h0/h1 and agg1/tmp are
// stored as packed bf16 pairs (uint32) to (a) stay within ws_size (~58.8 MB
// total — round-0 used ~110 MB and overflowed d_ws, corrupting the pristine
// input copies => post-timing divergence) and (b) halve gather traffic.
// ---------------------------------------------------------------------------

static inline int ceil_div(int a, int b) { return (a + b - 1) / b; }

typedef unsigned int uint;

// RTNE float -> bf16
__device__ __forceinline__ unsigned short f2bf(float f) {
  uint u = __float_as_uint(f);
  u += 0x7fffu + ((u >> 16) & 1u);
  return (unsigned short)(u >> 16);
}
__device__ __forceinline__ uint pack2(float lo, float hi) {
  return (uint)f2bf(lo) | ((uint)f2bf(hi) << 16);
}
__device__ __forceinline__ float unpack_lo(uint u) { return __uint_as_float(u << 16); }
__device__ __forceinline__ float unpack_hi(uint u) { return __uint_as_float(u & 0xffff0000u); }

// ---- CSR build ------------------------------------------------------------

__global__ __launch_bounds__(256) void k_hist(const int* __restrict__ dst,
                                              int* __restrict__ counts, int E) {
  int e = blockIdx.x * 256 + threadIdx.x;
  if (e < E) atomicAdd(&counts[dst[e]], 1);
}

__global__ __launch_bounds__(256) void k_scan1(const int* __restrict__ counts,
                                               int* __restrict__ excl,
                                               int* __restrict__ bsums, int N) {
  __shared__ int tmp[256];
  int i = blockIdx.x * 256 + threadIdx.x;
  int v = (i < N) ? counts[i] : 0;
  tmp[threadIdx.x] = v;
  __syncthreads();
  for (int off = 1; off < 256; off <<= 1) {
    int t = (threadIdx.x >= off) ? tmp[threadIdx.x - off] : 0;
    __syncthreads();
    tmp[threadIdx.x] += t;
    __syncthreads();
  }
  if (i < N) excl[i] = tmp[threadIdx.x] - v;  // block-local exclusive
  if (threadIdx.x == 255) bsums[blockIdx.x] = tmp[255];
}

__global__ __launch_bounds__(512) void k_scan2(int* __restrict__ bsums, int nb) {
  __shared__ int tmp[512];
  int v = (threadIdx.x < nb) ? bsums[threadIdx.x] : 0;
  tmp[threadIdx.x] = v;
  __syncthreads();
  for (int off = 1; off < 512; off <<= 1) {
    int t = (threadIdx.x >= off) ? tmp[threadIdx.x - off] : 0;
    __syncthreads();
    tmp[threadIdx.x] += t;
    __syncthreads();
  }
  if (threadIdx.x < nb) bsums[threadIdx.x] = tmp[threadIdx.x] - v;  // exclusive
}

__global__ __launch_bounds__(256) void k_scan3(int* __restrict__ excl,
                                               const int* __restrict__ bsums, int N) {
  int i = blockIdx.x * 256 + threadIdx.x;
  if (i < N) excl[i] += bsums[blockIdx.x];
}

__global__ __launch_bounds__(256) void k_fill(const int* __restrict__ src,
                                              const int* __restrict__ dst,
                                              const int* __restrict__ rowst,
                                              int* __restrict__ cursor,
                                              int* __restrict__ csr, int E) {
  int e = blockIdx.x * 256 + threadIdx.x;
  if (e < E) {
    int d = dst[e];
    int p = atomicAdd(&cursor[d], 1);
    csr[rowst[d] + p] = src[e];
  }
}

// ---- Aggregation layer 0: fp32 x (N x 64) -> fp32 agg (N x 64) ------------

__global__ __launch_bounds__(256) void k_agg0(const float* __restrict__ x,
                                              const int* __restrict__ rowst,
                                              const int* __restrict__ deg,
                                              const int* __restrict__ csr,
                                              float* __restrict__ agg, int N) {
  int lane = threadIdx.x & 63;
  int wid = (blockIdx.x * 256 + threadIdx.x) >> 6;
  int nw = (gridDim.x * 256) >> 6;
  for (int n = wid; n < N; n += nw) {
    int rs = rowst[n], d = deg[n];
    float mx = -INFINITY;
    int i = 0;
    for (; i + 3 < d; i += 4) {
      int s0 = csr[rs + i], s1 = csr[rs + i + 1];
      int s2 = csr[rs + i + 2], s3 = csr[rs + i + 3];
      float v0 = x[(size_t)s0 * 64 + lane];
      float v1 = x[(size_t)s1 * 64 + lane];
      float v2 = x[(size_t)s2 * 64 + lane];
      float v3 = x[(size_t)s3 * 64 + lane];
      mx = fmaxf(mx, fmaxf(fmaxf(v0, v1), fmaxf(v2, v3)));
    }
    for (; i < d; i++) {
      int s = csr[rs + i];
      mx = fmaxf(mx, x[(size_t)s * 64 + lane]);
    }
    agg[(size_t)n * 64 + lane] = (d > 0) ? mx : 0.0f;
  }
}

// ---- Aggregation layer 1: bf16-pair h0 (N x 64 uints) -> bf16-pair agg ----
// Max of bf16 values is bf16-representable -> truncation repack is exact.

__global__ __launch_bounds__(256) void k_agg1(const uint* __restrict__ h,
                                              const int* __restrict__ rowst,
                                              const int* __restrict__ deg,
                                              const int* __restrict__ csr,
                                              uint* __restrict__ agg, int N) {
  int lane = threadIdx.x & 63;
  int wid = (blockIdx.x * 256 + threadIdx.x) >> 6;
  int nw = (gridDim.x * 256) >> 6;
  for (int n = wid; n < N; n += nw) {
    int rs = rowst[n], d = deg[n];
    float mlo = -INFINITY, mhi = -INFINITY;
    int i = 0;
    for (; i + 3 < d; i += 4) {
      uint u0 = h[(size_t)csr[rs + i] * 64 + lane];
      uint u1 = h[(size_t)csr[rs + i + 1] * 64 + lane];
      uint u2 = h[(size_t)csr[rs + i + 2] * 64 + lane];
      uint u3 = h[(size_t)csr[rs + i + 3] * 64 + lane];
      mlo = fmaxf(mlo, fmaxf(fmaxf(unpack_lo(u0), unpack_lo(u1)),
                             fmaxf(unpack_lo(u2), unpack_lo(u3))));
      mhi = fmaxf(mhi, fmaxf(fmaxf(unpack_hi(u0), unpack_hi(u1)),
                             fmaxf(unpack_hi(u2), unpack_hi(u3))));
    }
    for (; i < d; i++) {
      uint u = h[(size_t)csr[rs + i] * 64 + lane];
      mlo = fmaxf(mlo, unpack_lo(u));
      mhi = fmaxf(mhi, unpack_hi(u));
    }
    uint packed = (__float_as_uint(mhi) & 0xffff0000u) | (__float_as_uint(mlo) >> 16);
    agg[(size_t)n * 64 + lane] = (d > 0) ? packed : 0u;
  }
}

// ---- Layer 0 linear + LN + ReLU -> packed bf16 h0 -------------------------
// Lane l produces features 2l, 2l+1 (so output packs naturally).

__global__ __launch_bounds__(256) void k_lin0(
    const float* __restrict__ x, const float* __restrict__ agg,
    const float* __restrict__ Wl, const float* __restrict__ bl,
    const float* __restrict__ Wr, const float* __restrict__ g,
    const float* __restrict__ be, uint* __restrict__ h0, int N) {
  __shared__ float sWl[64 * 128];  // sWl[k*128+j] = Wl[j][k]  (32 KB)
  __shared__ float sWr[64 * 128];
  for (int i = threadIdx.x; i < 64 * 128; i += 256) {
    int j = i >> 6, k = i & 63;
    sWl[k * 128 + j] = Wl[i];
    sWr[k * 128 + j] = Wr[i];
  }
  __syncthreads();
  int lane = threadIdx.x & 63;
  int wid = (blockIdx.x * 256 + threadIdx.x) >> 6;
  int nw = (gridDim.x * 256) >> 6;
  float2 blv = ((const float2*)bl)[lane];
  float2 gv = ((const float2*)g)[lane];
  float2 bev = ((const float2*)be)[lane];
  for (int n = wid; n < N; n += nw) {
    float av = agg[(size_t)n * 64 + lane];  // feature = lane
    float xv = x[(size_t)n * 64 + lane];
    float acc0 = blv.x, acc1 = blv.y;       // j = 2*lane, 2*lane+1
#pragma unroll
    for (int k = 0; k < 64; k++) {
      float a = __shfl(av, k);
      float b = __shfl(xv, k);
      float2 wl = *(const float2*)&sWl[k * 128 + 2 * lane];
      float2 wr = *(const float2*)&sWr[k * 128 + 2 * lane];
      acc0 += a * wl.x + b * wr.x;
      acc1 += a * wl.y + b * wr.y;
    }
    float s = acc0 + acc1;
#pragma unroll
    for (int off = 32; off; off >>= 1) s += __shfl_xor(s, off);
    float mu = s * (1.0f / 128.0f);
    float d0 = acc0 - mu, d1 = acc1 - mu;
    float q = d0 * d0 + d1 * d1;
#pragma unroll
    for (int off = 32; off; off >>= 1) q += __shfl_xor(q, off);
    float rstd = rsqrtf(q * (1.0f / 128.0f) + 1e-5f);
    float r0 = fmaxf(d0 * rstd * gv.x + bev.x, 0.0f);
    float r1 = fmaxf(d1 * rstd * gv.y + bev.y, 0.0f);
    h0[(size_t)n * 64 + lane] = pack2(r0, r1);
  }
}

// ---- Layer 1 part A: tmp = agg1 @ Wl1.T + bl1 (in-place, bf16-pair) -------

__global__ __launch_bounds__(256) void k_lin1a(uint* __restrict__ agg,
                                               const float* __restrict__ Wl,
                                               const float* __restrict__ bl, int N) {
  __shared__ float sW[128 * 128];  // sW[k*128+j] = Wl[j][k]  (64 KB)
  for (int i = threadIdx.x; i < 128 * 128; i += 256) {
    int j = i >> 7, k = i & 127;
    sW[k * 128 + j] = Wl[i];
  }
  __syncthreads();
  int lane = threadIdx.x & 63;
  int wid = (blockIdx.x * 256 + threadIdx.x) >> 6;
  int nw = (gridDim.x * 256) >> 6;
  float2 blv = ((const float2*)bl)[lane];
  for (int n = wid; n < N; n += nw) {
    uint u = agg[(size_t)n * 64 + lane];  // features 2l (lo), 2l+1 (hi)
    float a_lo = unpack_lo(u), a_hi = unpack_hi(u);
    float acc0 = blv.x, acc1 = blv.y;
#pragma unroll
    for (int k2 = 0; k2 < 64; k2++) {
      float ae = __shfl(a_lo, k2);  // feature 2*k2
      float ao = __shfl(a_hi, k2);  // feature 2*k2+1
      float2 we = *(const float2*)&sW[(2 * k2) * 128 + 2 * lane];
      float2 wo = *(const float2*)&sW[(2 * k2 + 1) * 128 + 2 * lane];
      acc0 += ae * we.x + ao * wo.x;
      acc1 += ae * we.y + ao * wo.y;
    }
    agg[(size_t)n * 64 + lane] = pack2(acc0, acc1);  // row fully read above
  }
}

// ---- Layer 1 part B: h1 = LNrelu(tmp + h0 @ Wr1.T), in-place over h0 ------

__global__ __launch_bounds__(256) void k_lin1b(const uint* __restrict__ tmp,
                                               uint* __restrict__ h0,
                                               const float* __restrict__ Wr,
                                               const float* __restrict__ g,
                                               const float* __restrict__ be, int N) {
  __shared__ float sW[128 * 128];  // sW[k*128+j] = Wr[j][k]
  for (int i = threadIdx.x; i < 128 * 128; i += 256) {
    int j = i >> 7, k = i & 127;
    sW[k * 128 + j] = Wr[i];
  }
  __syncthreads();
  int lane = threadIdx.x & 63;
  int wid = (blockIdx.x * 256 + threadIdx.x) >> 6;
  int nw = (gridDim.x * 256) >> 6;
  float2 gv = ((const float2*)g)[lane];
  float2 bev = ((const float2*)be)[lane];
  for (int n = wid; n < N; n += nw) {
    uint ux = h0[(size_t)n * 64 + lane];
    uint ut = tmp[(size_t)n * 64 + lane];
    float x_lo = unpack_lo(ux), x_hi = unpack_hi(ux);
    float acc0 = unpack_lo(ut), acc1 = unpack_hi(ut);
#pragma unroll
    for (int k2 = 0; k2 < 64; k2++) {
      float ae = __shfl(x_lo, k2);
      float ao = __shfl(x_hi, k2);
      float2 we = *(const float2*)&sW[(2 * k2) * 128 + 2 * lane];
      float2 wo = *(const float2*)&sW[(2 * k2 + 1) * 128 + 2 * lane];
      acc0 += ae * we.x + ao * wo.x;
      acc1 += ae * we.y + ao * wo.y;
    }
    float s = acc0 + acc1;
#pragma unroll
    for (int off = 32; off; off >>= 1) s += __shfl_xor(s, off);
    float mu = s * (1.0f / 128.0f);
    float d0 = acc0 - mu, d1 = acc1 - mu;
    float q = d0 * d0 + d1 * d1;
#pragma unroll
    for (int off = 32; off; off >>= 1) q += __shfl_xor(q, off);
    float rstd = rsqrtf(q * (1.0f / 128.0f) + 1e-5f);
    float r0 = fmaxf(d0 * rstd * gv.x + bev.x, 0.0f);
    float r1 = fmaxf(d1 * rstd * gv.y + bev.y, 0.0f);
    h0[(size_t)n * 64 + lane] = pack2(r0, r1);
  }
}

// ---- MLP head: sigmoid(relu(h1@W1.T+b1)@W2.T + b2) ------------------------

__global__ __launch_bounds__(256) void k_mlp(const uint* __restrict__ h1,
                                             const float* __restrict__ W1,
                                             const float* __restrict__ b1,
                                             const float* __restrict__ W2,
                                             const float* __restrict__ b2,
                                             float* __restrict__ out, int N) {
  __shared__ float sW[128 * 64];  // sW[k*64+j] = W1[j][k]  (32 KB)
  for (int i = threadIdx.x; i < 64 * 128; i += 256) {
    int j = i >> 7, k = i & 127;
    sW[k * 64 + j] = W1[i];
  }
  __syncthreads();
  int lane = threadIdx.x & 63;
  int wid = (blockIdx.x * 256 + threadIdx.x) >> 6;
  int nw = (gridDim.x * 256) >> 6;
  float b1v = b1[lane];
  float w2v = W2[lane];
  float b2v = b2[0];
  for (int n = wid; n < N; n += nw) {
    uint u = h1[(size_t)n * 64 + lane];
    float x_lo = unpack_lo(u), x_hi = unpack_hi(u);
    float z = b1v;
#pragma unroll
    for (int k2 = 0; k2 < 64; k2++) {
      float e = __shfl(x_lo, k2);
      float o = __shfl(x_hi, k2);
      z += e * sW[(2 * k2) * 64 + lane] + o * sW[(2 * k2 + 1) * 64 + lane];
    }
    float r = fmaxf(z, 0.0f) * w2v;
#pragma unroll
    for (int off = 32; off; off >>= 1) r += __shfl_xor(r, off);
    if (lane == 0) out[n] = 1.0f / (1.0f + expf(-(r + b2v)));
  }
}

// ---------------------------------------------------------------------------

extern "C" void kernel_launch(void* const* d_in, const int* in_sizes, int n_in,
                              void* d_out, int out_size, void* d_ws, size_t ws_size,
                              hipStream_t stream) {
  const float* x = (const float*)d_in[0];
  const int* ei = (const int*)d_in[1];
  const float* Wl0 = (const float*)d_in[2];
  const float* bl0 = (const float*)d_in[3];
  const float* Wr0 = (const float*)d_in[4];
  const float* g0 = (const float*)d_in[5];
  const float* be0 = (const float*)d_in[6];
  const float* Wl1 = (const float*)d_in[7];
  const float* bl1 = (const float*)d_in[8];
  const float* Wr1 = (const float*)d_in[9];
  const float* g1 = (const float*)d_in[10];
  const float* be1 = (const float*)d_in[11];
  const float* W1 = (const float*)d_in[12];
  const float* b1 = (const float*)d_in[13];
  const float* W2 = (const float*)d_in[14];
  const float* b2 = (const float*)d_in[15];
  float* out = (float*)d_out;

  const int N = in_sizes[0] / 64;
  const int E = in_sizes[1] / 2;
  const int* src = ei;
  const int* dst = ei + E;

  // Workspace layout (~58.8 MB total; round-0's 110 MB overflowed d_ws):
  char* ws = (char*)d_ws;
  size_t off = 0;
  auto alloc = [&](size_t bytes) -> void* {
    void* p = ws + off;
    off = (off + bytes + 255) & ~(size_t)255;
    return p;
  };
  int* counts = (int*)alloc((size_t)N * 4);
  int* rowst = (int*)alloc((size_t)N * 4);
  int* cursor = (int*)alloc((size_t)N * 4);
  int* bsums = (int*)alloc(512 * 4);
  int* csr = (int*)alloc((size_t)E * 4);
  // Region A: layer-0 agg (N x 64 fp32) THEN layer-1 agg/tmp (N x 64 uints).
  // Lifetimes disjoint (agg0 dead after k_lin0). Both are 25.6 MB.
  void* regionA = alloc((size_t)N * 64 * 4);
  uint* h0 = (uint*)alloc((size_t)N * 64 * 4);  // bf16-pair h0 / h1 (25.6 MB)

  float* agg0 = (float*)regionA;
  uint* agg1 = (uint*)regionA;

  hipMemsetAsync(counts, 0, (size_t)N * 4, stream);
  hipMemsetAsync(cursor, 0, (size_t)N * 4, stream);

  int nb1 = ceil_div(N, 256);
  k_hist<<<ceil_div(E, 256), 256, 0, stream>>>(dst, counts, E);
  k_scan1<<<nb1, 256, 0, stream>>>(counts, rowst, bsums, N);
  k_scan2<<<1, 512, 0, stream>>>(bsums, nb1);
  k_scan3<<<nb1, 256, 0, stream>>>(rowst, bsums, N);
  k_fill<<<ceil_div(E, 256), 256, 0, stream>>>(src, dst, rowst, cursor, csr, E);

  k_agg0<<<2048, 256, 0, stream>>>(x, rowst, counts, csr, agg0, N);
  k_lin0<<<512, 256, 0, stream>>>(x, agg0, Wl0, bl0, Wr0, g0, be0, h0, N);
  k_agg1<<<2048, 256, 0, stream>>>(h0, rowst, counts, csr, agg1, N);
  k_lin1a<<<512, 256, 0, stream>>>(agg1, Wl1, bl1, N);
  k_lin1b<<<512, 256, 0, stream>>>(agg1, h0, Wr1, g1, be1, N);
  k_mlp<<<1024, 256, 0, stream>>>(h0, W1, b1, W2, b2, out, N);
}

// Round 3
// 483.791 us; speedup vs baseline: 2.5989x; 2.5989x over previous
//
#include <hip/hip_runtime.h>
#include <math.h>

// ---------------------------------------------------------------------------
// GraphSAGE (max aggr) x2 + LN + ReLU + MLP head + sigmoid.
// CSR build -> gather-max aggregation (bf16) -> MFMA GEMM linear layers with
// fused LN/ReLU/sigmoid epilogues. All dense layers use 16x16x32 bf16 MFMA,
// B pre-packed into LDS in fragment order (lane-contiguous b128, no bank
// conflicts), 2 node-tiles per wave. Layer-0 weights split hi+lo bf16 for
// near-fp32 weight precision. Workspace kept at 58.8 MB via region reuse
// (the 110 MB round-0 layout overflowed d_ws).
// ---------------------------------------------------------------------------

static inline int ceil_div(int a, int b) { return (a + b - 1) / b; }

typedef unsigned int uint;
typedef __attribute__((ext_vector_type(8))) short short8;
typedef __attribute__((ext_vector_type(4))) float f32x4;

// RTNE float -> bf16
__device__ __forceinline__ unsigned short f2bf(float f) {
  uint u = __float_as_uint(f);
  u += 0x7fffu + ((u >> 16) & 1u);
  return (unsigned short)(u >> 16);
}
__device__ __forceinline__ float bfval(unsigned short b) {
  return __uint_as_float((uint)b << 16);
}
__device__ __forceinline__ uint pack2(float lo, float hi) {
  return (uint)f2bf(lo) | ((uint)f2bf(hi) << 16);
}
__device__ __forceinline__ float unpack_lo(uint u) { return __uint_as_float(u << 16); }
__device__ __forceinline__ float unpack_hi(uint u) { return __uint_as_float(u & 0xffff0000u); }

// ---- CSR build ------------------------------------------------------------

__global__ __launch_bounds__(256) void k_hist(const int* __restrict__ dst,
                                              int* __restrict__ counts, int E) {
  int e = blockIdx.x * 256 + threadIdx.x;
  if (e < E) atomicAdd(&counts[dst[e]], 1);
}

__global__ __launch_bounds__(256) void k_scan1(const int* __restrict__ counts,
                                               int* __restrict__ excl,
                                               int* __restrict__ bsums, int N) {
  __shared__ int tmp[256];
  int i = blockIdx.x * 256 + threadIdx.x;
  int v = (i < N) ? counts[i] : 0;
  tmp[threadIdx.x] = v;
  __syncthreads();
  for (int off = 1; off < 256; off <<= 1) {
    int t = (threadIdx.x >= off) ? tmp[threadIdx.x - off] : 0;
    __syncthreads();
    tmp[threadIdx.x] += t;
    __syncthreads();
  }
  if (i < N) excl[i] = tmp[threadIdx.x] - v;
  if (threadIdx.x == 255) bsums[blockIdx.x] = tmp[255];
}

__global__ __launch_bounds__(512) void k_scan2(int* __restrict__ bsums, int nb) {
  __shared__ int tmp[512];
  int v = (threadIdx.x < nb) ? bsums[threadIdx.x] : 0;
  tmp[threadIdx.x] = v;
  __syncthreads();
  for (int off = 1; off < 512; off <<= 1) {
    int t = (threadIdx.x >= off) ? tmp[threadIdx.x - off] : 0;
    __syncthreads();
    tmp[threadIdx.x] += t;
    __syncthreads();
  }
  if (threadIdx.x < nb) bsums[threadIdx.x] = tmp[threadIdx.x] - v;
}

__global__ __launch_bounds__(256) void k_scan3(int* __restrict__ excl,
                                               const int* __restrict__ bsums, int N) {
  int i = blockIdx.x * 256 + threadIdx.x;
  if (i < N) excl[i] += bsums[blockIdx.x];
}

__global__ __launch_bounds__(256) void k_fill(const int* __restrict__ src,
                                              const int* __restrict__ dst,
                                              const int* __restrict__ rowst,
                                              int* __restrict__ cursor,
                                              int* __restrict__ csr, int E) {
  int e = blockIdx.x * 256 + threadIdx.x;
  if (e < E) {
    int d = dst[e];
    int p = atomicAdd(&cursor[d], 1);
    csr[rowst[d] + p] = src[e];
  }
}

// ---- Prep: x fp32 [N][64] -> packed bf16 uint [N][32] ---------------------

__global__ __launch_bounds__(256) void k_prep(const float* __restrict__ x,
                                              uint* __restrict__ xb, int total) {
  int i = blockIdx.x * 256 + threadIdx.x;
  if (i < total) {
    float2 v = ((const float2*)x)[i];
    xb[i] = pack2(v.x, v.y);
  }
}

// ---- Aggregation layer 0: bf16 xb (N x 32 uints), 2 nodes per wave --------

__global__ __launch_bounds__(256) void k_agg0b(const uint* __restrict__ xb,
                                               const int* __restrict__ rowst,
                                               const int* __restrict__ deg,
                                               const int* __restrict__ csr,
                                               uint* __restrict__ agg, int N) {
  int lane = threadIdx.x & 63;
  int sub = lane >> 5;  // which of the 2 nodes
  int l = lane & 31;
  int w = (blockIdx.x * 256 + threadIdx.x) >> 6;
  int nw = (gridDim.x * 256) >> 6;
  for (int n0 = w * 2; n0 < N; n0 += nw * 2) {
    int n = n0 + sub;
    if (n >= N) continue;
    int rs = rowst[n], d = deg[n];
    float mlo = -INFINITY, mhi = -INFINITY;
    int i = 0;
    for (; i + 3 < d; i += 4) {
      uint u0 = xb[(size_t)csr[rs + i] * 32 + l];
      uint u1 = xb[(size_t)csr[rs + i + 1] * 32 + l];
      uint u2 = xb[(size_t)csr[rs + i + 2] * 32 + l];
      uint u3 = xb[(size_t)csr[rs + i + 3] * 32 + l];
      mlo = fmaxf(mlo, fmaxf(fmaxf(unpack_lo(u0), unpack_lo(u1)),
                             fmaxf(unpack_lo(u2), unpack_lo(u3))));
      mhi = fmaxf(mhi, fmaxf(fmaxf(unpack_hi(u0), unpack_hi(u1)),
                             fmaxf(unpack_hi(u2), unpack_hi(u3))));
    }
    for (; i < d; i++) {
      uint u = xb[(size_t)csr[rs + i] * 32 + l];
      mlo = fmaxf(mlo, unpack_lo(u));
      mhi = fmaxf(mhi, unpack_hi(u));
    }
    uint packed = (__float_as_uint(mhi) & 0xffff0000u) | (__float_as_uint(mlo) >> 16);
    agg[(size_t)n * 32 + l] = (d > 0) ? packed : 0u;
  }
}

// ---- Aggregation layer 1: bf16-pair h0 (N x 64 uints) ---------------------

__global__ __launch_bounds__(256) void k_agg1(const uint* __restrict__ h,
                                              const int* __restrict__ rowst,
                                              const int* __restrict__ deg,
                                              const int* __restrict__ csr,
                                              uint* __restrict__ agg, int N) {
  int lane = threadIdx.x & 63;
  int wid = (blockIdx.x * 256 + threadIdx.x) >> 6;
  int nw = (gridDim.x * 256) >> 6;
  for (int n = wid; n < N; n += nw) {
    int rs = rowst[n], d = deg[n];
    float mlo = -INFINITY, mhi = -INFINITY;
    int i = 0;
    for (; i + 3 < d; i += 4) {
      uint u0 = h[(size_t)csr[rs + i] * 64 + lane];
      uint u1 = h[(size_t)csr[rs + i + 1] * 64 + lane];
      uint u2 = h[(size_t)csr[rs + i + 2] * 64 + lane];
      uint u3 = h[(size_t)csr[rs + i + 3] * 64 + lane];
      mlo = fmaxf(mlo, fmaxf(fmaxf(unpack_lo(u0), unpack_lo(u1)),
                             fmaxf(unpack_lo(u2), unpack_lo(u3))));
      mhi = fmaxf(mhi, fmaxf(fmaxf(unpack_hi(u0), unpack_hi(u1)),
                             fmaxf(unpack_hi(u2), unpack_hi(u3))));
    }
    for (; i < d; i++) {
      uint u = h[(size_t)csr[rs + i] * 64 + lane];
      mlo = fmaxf(mlo, unpack_lo(u));
      mhi = fmaxf(mhi, unpack_hi(u));
    }
    uint packed = (__float_as_uint(mhi) & 0xffff0000u) | (__float_as_uint(mlo) >> 16);
    agg[(size_t)n * 64 + lane] = (d > 0) ? packed : 0u;
  }
}

// ---- Layer 0: h0 = LNrelu([agg0|x] @ [Wl0|Wr0]^T + bl0) -------------------
// MFMA 16x16x32 bf16. K=128 logical; weights split hi+lo bf16 -> 8 K-steps
// with a[ks&3]. B packed in LDS in fragment order: entry (ks, jt, lane) =
// 8 bf16 of row j=jt*16+(lane&15), k = (ks&3)*32 + (lane>>4)*8 .. +8.

__global__ __launch_bounds__(256) void k_lin0(
    const uint* __restrict__ agg,  // N x 32 uints (bf16 [N][64])
    const uint* __restrict__ xb,   // N x 32 uints
    const float* __restrict__ Wl, const float* __restrict__ bl,
    const float* __restrict__ Wr, const float* __restrict__ g,
    const float* __restrict__ be, unsigned short* __restrict__ hout, int N) {
  __shared__ uint4 sB[4096];  // 64 KB: [ks 0..7][jt 0..7][lane 0..63]
  for (int e = threadIdx.x; e < 4096; e += 256) {
    int lane = e & 63, jt = (e >> 6) & 7, ks = e >> 9;
    int m = lane & 15, q = lane >> 4;
    int j = jt * 16 + m;
    int half = ks >> 2;             // 0 = hi, 1 = lo
    int kk = (ks & 3) * 32 + q * 8; // 0..120
    const float* srcr = (kk < 64) ? (Wl + (size_t)j * 64 + kk)
                                  : (Wr + (size_t)j * 64 + (kk - 64));
    float4 w0 = ((const float4*)srcr)[0];
    float4 w1 = ((const float4*)srcr)[1];
    float v[8] = {w0.x, w0.y, w0.z, w0.w, w1.x, w1.y, w1.z, w1.w};
    unsigned short b16[8];
#pragma unroll
    for (int i = 0; i < 8; i++) {
      unsigned short hi = f2bf(v[i]);
      b16[i] = half ? f2bf(v[i] - bfval(hi)) : hi;
    }
    uint4 p;
    p.x = (uint)b16[0] | ((uint)b16[1] << 16);
    p.y = (uint)b16[2] | ((uint)b16[3] << 16);
    p.z = (uint)b16[4] | ((uint)b16[5] << 16);
    p.w = (uint)b16[6] | ((uint)b16[7] << 16);
    sB[e] = p;
  }
  __syncthreads();

  int lane = threadIdx.x & 63, m = lane & 15, q = lane >> 4;
  int w = (blockIdx.x * 256 + threadIdx.x) >> 6;
  int nw = (gridDim.x * 256) >> 6;
  int pairs = (N + 31) / 32;
  float blv[8], gv[8], bev[8];
#pragma unroll
  for (int jt = 0; jt < 8; jt++) {
    blv[jt] = bl[jt * 16 + m];
    gv[jt] = g[jt * 16 + m];
    bev[jt] = be[jt * 16 + m];
  }
  for (int p = w; p < pairs; p += nw) {
    int b0 = p * 32;
    short8 a[2][4];
#pragma unroll
    for (int t = 0; t < 2; t++) {
      int row = b0 + t * 16 + m;
      const uint* r0 = agg + (size_t)row * 32;
      const uint* r1 = xb + (size_t)row * 32;
#pragma unroll
      for (int ks = 0; ks < 4; ks++) {
        const uint* base = (ks < 2) ? r0 : r1;
        a[t][ks] = __builtin_bit_cast(short8, *(const uint4*)(base + (ks & 1) * 16 + q * 4));
      }
    }
    f32x4 acc[2][8];
#pragma unroll
    for (int t = 0; t < 2; t++)
#pragma unroll
      for (int jt = 0; jt < 8; jt++) acc[t][jt] = {0.f, 0.f, 0.f, 0.f};
#pragma unroll
    for (int ks = 0; ks < 8; ks++) {
#pragma unroll
      for (int jt = 0; jt < 8; jt++) {
        short8 b = __builtin_bit_cast(short8, sB[(ks * 8 + jt) * 64 + lane]);
        acc[0][jt] = __builtin_amdgcn_mfma_f32_16x16x32_bf16(a[0][ks & 3], b, acc[0][jt], 0, 0, 0);
        acc[1][jt] = __builtin_amdgcn_mfma_f32_16x16x32_bf16(a[1][ks & 3], b, acc[1][jt], 0, 0, 0);
      }
    }
#pragma unroll
    for (int t = 0; t < 2; t++) {
      float s1[4] = {0.f, 0.f, 0.f, 0.f}, s2[4] = {0.f, 0.f, 0.f, 0.f};
#pragma unroll
      for (int jt = 0; jt < 8; jt++) {
        float bb = blv[jt];
#pragma unroll
        for (int r = 0; r < 4; r++) {
          float v = acc[t][jt][r] + bb;
          s1[r] += v;
          s2[r] += v * v;
        }
      }
#pragma unroll
      for (int off = 1; off < 16; off <<= 1) {
#pragma unroll
        for (int r = 0; r < 4; r++) {
          s1[r] += __shfl_xor(s1[r], off);
          s2[r] += __shfl_xor(s2[r], off);
        }
      }
      float mu[4], rstd[4];
#pragma unroll
      for (int r = 0; r < 4; r++) {
        mu[r] = s1[r] * (1.0f / 128.0f);
        float var = s2[r] * (1.0f / 128.0f) - mu[r] * mu[r];
        rstd[r] = rsqrtf(var + 1e-5f);
      }
      int nodeb = b0 + t * 16 + q * 4;
#pragma unroll
      for (int jt = 0; jt < 8; jt++) {
        float bb = blv[jt];
#pragma unroll
        for (int r = 0; r < 4; r++) {
          int node = nodeb + r;
          if (node < N) {
            float v = acc[t][jt][r] + bb;
            float o = fmaxf((v - mu[r]) * rstd[r] * gv[jt] + bev[jt], 0.0f);
            hout[(size_t)node * 128 + jt * 16 + m] = f2bf(o);
          }
        }
      }
    }
  }
}

// ---- Layer 1: h1 = LNrelu([agg1|h0] @ [Wl1|Wr1]^T + bl1), in-place --------
// K=256, plain bf16 weights. h1 written over agg1 (each row fully read by its
// owning wave before the store). `agg` intentionally NOT __restrict__.

__global__ __launch_bounds__(256) void k_lin1(
    uint* agg,                     // N x 64 uints; becomes h1 (bf16 [N][128])
    const uint* __restrict__ h0,   // N x 64 uints
    const float* __restrict__ Wl, const float* __restrict__ bl,
    const float* __restrict__ Wr, const float* __restrict__ g,
    const float* __restrict__ be, int N) {
  __shared__ uint4 sB[4096];  // 64 KB
  for (int e = threadIdx.x; e < 4096; e += 256) {
    int lane = e & 63, jt = (e >> 6) & 7, ks = e >> 9;
    int m = lane & 15, q = lane >> 4;
    int j = jt * 16 + m;
    int k0 = ks * 32 + q * 8;  // 0..248
    const float* srcr = (k0 < 128) ? (Wl + (size_t)j * 128 + k0)
                                   : (Wr + (size_t)j * 128 + (k0 - 128));
    float4 w0 = ((const float4*)srcr)[0];
    float4 w1 = ((const float4*)srcr)[1];
    uint4 p;
    p.x = pack2(w0.x, w0.y);
    p.y = pack2(w0.z, w0.w);
    p.z = pack2(w1.x, w1.y);
    p.w = pack2(w1.z, w1.w);
    sB[e] = p;
  }
  __syncthreads();

  int lane = threadIdx.x & 63, m = lane & 15, q = lane >> 4;
  int w = (blockIdx.x * 256 + threadIdx.x) >> 6;
  int nw = (gridDim.x * 256) >> 6;
  int pairs = (N + 31) / 32;
  float blv[8], gv[8], bev[8];
#pragma unroll
  for (int jt = 0; jt < 8; jt++) {
    blv[jt] = bl[jt * 16 + m];
    gv[jt] = g[jt * 16 + m];
    bev[jt] = be[jt * 16 + m];
  }
  unsigned short* hout = (unsigned short*)agg;
  for (int p = w; p < pairs; p += nw) {
    int b0 = p * 32;
    short8 a[2][8];
#pragma unroll
    for (int t = 0; t < 2; t++) {
      int row = b0 + t * 16 + m;
      const uint* r0 = agg + (size_t)row * 64;
      const uint* r1 = h0 + (size_t)row * 64;
#pragma unroll
      for (int ks = 0; ks < 8; ks++) {
        const uint* base = (ks < 4) ? r0 : r1;
        a[t][ks] = __builtin_bit_cast(short8, *(const uint4*)(base + (ks & 3) * 16 + q * 4));
      }
    }
    f32x4 acc[2][8];
#pragma unroll
    for (int t = 0; t < 2; t++)
#pragma unroll
      for (int jt = 0; jt < 8; jt++) acc[t][jt] = {0.f, 0.f, 0.f, 0.f};
#pragma unroll
    for (int ks = 0; ks < 8; ks++) {
#pragma unroll
      for (int jt = 0; jt < 8; jt++) {
        short8 b = __builtin_bit_cast(short8, sB[(ks * 8 + jt) * 64 + lane]);
        acc[0][jt] = __builtin_amdgcn_mfma_f32_16x16x32_bf16(a[0][ks], b, acc[0][jt], 0, 0, 0);
        acc[1][jt] = __builtin_amdgcn_mfma_f32_16x16x32_bf16(a[1][ks], b, acc[1][jt], 0, 0, 0);
      }
    }
#pragma unroll
    for (int t = 0; t < 2; t++) {
      float s1[4] = {0.f, 0.f, 0.f, 0.f}, s2[4] = {0.f, 0.f, 0.f, 0.f};
#pragma unroll
      for (int jt = 0; jt < 8; jt++) {
        float bb = blv[jt];
#pragma unroll
        for (int r = 0; r < 4; r++) {
          float v = acc[t][jt][r] + bb;
          s1[r] += v;
          s2[r] += v * v;
        }
      }
#pragma unroll
      for (int off = 1; off < 16; off <<= 1) {
#pragma unroll
        for (int r = 0; r < 4; r++) {
          s1[r] += __shfl_xor(s1[r], off);
          s2[r] += __shfl_xor(s2[r], off);
        }
      }
      float mu[4], rstd[4];
#pragma unroll
      for (int r = 0; r < 4; r++) {
        mu[r] = s1[r] * (1.0f / 128.0f);
        float var = s2[r] * (1.0f / 128.0f) - mu[r] * mu[r];
        rstd[r] = rsqrtf(var + 1e-5f);
      }
      int nodeb = b0 + t * 16 + q * 4;
#pragma unroll
      for (int jt = 0; jt < 8; jt++) {
        float bb = blv[jt];
#pragma unroll
        for (int r = 0; r < 4; r++) {
          int node = nodeb + r;
          if (node < N) {
            float v = acc[t][jt][r] + bb;
            float o = fmaxf((v - mu[r]) * rstd[r] * gv[jt] + bev[jt], 0.0f);
            hout[(size_t)node * 128 + jt * 16 + m] = f2bf(o);
          }
        }
      }
    }
  }
}

// ---- MLP head: out = sigmoid(relu(h1@W1.T+b1) @ W2.T + b2) ----------------

__global__ __launch_bounds__(256) void k_mlp(const uint* __restrict__ h1,
                                             const float* __restrict__ W1,
                                             const float* __restrict__ b1,
                                             const float* __restrict__ W2,
                                             const float* __restrict__ b2,
                                             float* __restrict__ out, int N) {
  __shared__ uint4 sB[1024];  // 16 KB: [ks 0..3][jt 0..3][lane]
  for (int e = threadIdx.x; e < 1024; e += 256) {
    int lane = e & 63, jt = (e >> 6) & 3, ks = e >> 8;
    int m = lane & 15, q = lane >> 4;
    int j = jt * 16 + m;          // 0..63
    int k0 = ks * 32 + q * 8;     // 0..120
    const float* srcr = W1 + (size_t)j * 128 + k0;
    float4 w0 = ((const float4*)srcr)[0];
    float4 w1 = ((const float4*)srcr)[1];
    uint4 p;
    p.x = pack2(w0.x, w0.y);
    p.y = pack2(w0.z, w0.w);
    p.z = pack2(w1.x, w1.y);
    p.w = pack2(w1.z, w1.w);
    sB[e] = p;
  }
  __syncthreads();

  int lane = threadIdx.x & 63, m = lane & 15, q = lane >> 4;
  int w = (blockIdx.x * 256 + threadIdx.x) >> 6;
  int nw = (gridDim.x * 256) >> 6;
  int tiles = (N + 15) / 16;
  float b1v[4], w2v[4];
#pragma unroll
  for (int jt = 0; jt < 4; jt++) {
    b1v[jt] = b1[jt * 16 + m];
    w2v[jt] = W2[jt * 16 + m];
  }
  float b2v = b2[0];
  for (int tl = w; tl < tiles; tl += nw) {
    int b0 = tl * 16;
    int row = b0 + m;
    const uint* r0 = h1 + (size_t)row * 64;
    short8 a[4];
#pragma unroll
    for (int ks = 0; ks < 4; ks++)
      a[ks] = __builtin_bit_cast(short8, *(const uint4*)(r0 + ks * 16 + q * 4));
    f32x4 acc[4];
#pragma unroll
    for (int jt = 0; jt < 4; jt++) acc[jt] = {0.f, 0.f, 0.f, 0.f};
#pragma unroll
    for (int ks = 0; ks < 4; ks++) {
#pragma unroll
      for (int jt = 0; jt < 4; jt++) {
        short8 b = __builtin_bit_cast(short8, sB[(ks * 4 + jt) * 64 + lane]);
        acc[jt] = __builtin_amdgcn_mfma_f32_16x16x32_bf16(a[ks], b, acc[jt], 0, 0, 0);
      }
    }
    float part[4] = {0.f, 0.f, 0.f, 0.f};
#pragma unroll
    for (int jt = 0; jt < 4; jt++) {
#pragma unroll
      for (int r = 0; r < 4; r++)
        part[r] += fmaxf(acc[jt][r] + b1v[jt], 0.0f) * w2v[jt];
    }
#pragma unroll
    for (int off = 1; off < 16; off <<= 1) {
#pragma unroll
      for (int r = 0; r < 4; r++) part[r] += __shfl_xor(part[r], off);
    }
    if (m == 0) {
#pragma unroll
      for (int r = 0; r < 4; r++) {
        int node = b0 + q * 4 + r;
        if (node < N) out[node] = 1.0f / (1.0f + expf(-(part[r] + b2v)));
      }
    }
  }
}

// ---------------------------------------------------------------------------

extern "C" void kernel_launch(void* const* d_in, const int* in_sizes, int n_in,
                              void* d_out, int out_size, void* d_ws, size_t ws_size,
                              hipStream_t stream) {
  const float* x = (const float*)d_in[0];
  const int* ei = (const int*)d_in[1];
  const float* Wl0 = (const float*)d_in[2];
  const float* bl0 = (const float*)d_in[3];
  const float* Wr0 = (const float*)d_in[4];
  const float* g0 = (const float*)d_in[5];
  const float* be0 = (const float*)d_in[6];
  const float* Wl1 = (const float*)d_in[7];
  const float* bl1 = (const float*)d_in[8];
  const float* Wr1 = (const float*)d_in[9];
  const float* g1 = (const float*)d_in[10];
  const float* be1 = (const float*)d_in[11];
  const float* W1 = (const float*)d_in[12];
  const float* b1 = (const float*)d_in[13];
  const float* W2 = (const float*)d_in[14];
  const float* b2 = (const float*)d_in[15];
  float* out = (float*)d_out;

  const int N = in_sizes[0] / 64;
  const int E = in_sizes[1] / 2;
  const int* src = ei;
  const int* dst = ei + E;

  // Workspace (~58.8 MB peak, matches the passing round-1 footprint):
  //   misc (1.2 MB) + csr (6.4 MB) + regionX (25.6 MB) + h0 (25.6 MB)
  // regionX timeline: [xb | agg0b] -> agg1 -> h1 (in-place).
  char* ws = (char*)d_ws;
  size_t off = 0;
  auto alloc = [&](size_t bytes) -> void* {
    void* p = ws + off;
    off = (off + bytes + 255) & ~(size_t)255;
    return p;
  };
  int* counts = (int*)alloc((size_t)N * 4);
  int* rowst = (int*)alloc((size_t)N * 4);
  int* cursor = (int*)alloc((size_t)N * 4);
  int* bsums = (int*)alloc(512 * 4);
  int* csr = (int*)alloc((size_t)E * 4);
  uint* regionX = (uint*)alloc((size_t)N * 64 * 4);  // 25.6 MB
  uint* h0buf = (uint*)alloc((size_t)N * 64 * 4);    // 25.6 MB

  uint* xb = regionX;                    // N x 32 uints
  uint* agg0b = regionX + (size_t)N * 32;  // N x 32 uints
  uint* agg1 = regionX;                  // N x 64 uints (over dead xb/agg0b)

  hipMemsetAsync(counts, 0, (size_t)N * 4, stream);
  hipMemsetAsync(cursor, 0, (size_t)N * 4, stream);

  int nb1 = ceil_div(N, 256);
  k_prep<<<ceil_div(N * 32, 256), 256, 0, stream>>>(x, xb, N * 32);
  k_hist<<<ceil_div(E, 256), 256, 0, stream>>>(dst, counts, E);
  k_scan1<<<nb1, 256, 0, stream>>>(counts, rowst, bsums, N);
  k_scan2<<<1, 512, 0, stream>>>(bsums, nb1);
  k_scan3<<<nb1, 256, 0, stream>>>(rowst, bsums, N);
  k_fill<<<ceil_div(E, 256), 256, 0, stream>>>(src, dst, rowst, cursor, csr, E);

  k_agg0b<<<2048, 256, 0, stream>>>(xb, rowst, counts, csr, agg0b, N);
  k_lin0<<<512, 256, 0, stream>>>(agg0b, xb, Wl0, bl0, Wr0, g0, be0,
                                  (unsigned short*)h0buf, N);
  k_agg1<<<2048, 256, 0, stream>>>(h0buf, rowst, counts, csr, agg1, N);
  k_lin1<<<512, 256, 0, stream>>>(agg1, h0buf, Wl1, bl1, Wr1, g1, be1, N);
  k_mlp<<<512, 256, 0, stream>>>(agg1, W1, b1, W2, b2, out, N);
}

// Round 4
// 413.117 us; speedup vs baseline: 3.0435x; 1.1711x over previous
//
#include <hip/hip_runtime.h>
#include <math.h>

// ---------------------------------------------------------------------------
// GraphSAGE (max aggr) x2 + LN + ReLU + MLP head + sigmoid.
// CSR build via 2-level LDS-staged counting sort (no cross-XCD line
// ping-pong: round-3's k_fill had 16x write amplification, 107 MB for a
// 6.4 MB csr) -> gather-max aggregation with lane-parallel index loads ->
// MFMA GEMM linear layers with fused LN/ReLU/sigmoid epilogues.
// Workspace stays ~58.8 MB: bed (12.8 MB) aliases the h0 buffer (dead until
// k_lin0), h1 overwrites agg1 in-place.
// ---------------------------------------------------------------------------

static inline int ceil_div(int a, int b) { return (a + b - 1) / b; }

typedef unsigned int uint;
typedef __attribute__((ext_vector_type(8))) short short8;
typedef __attribute__((ext_vector_type(4))) float f32x4;

#define NBSHIFT 8     // bucket = 256 dst nodes
#define ACHUNK 4096   // edges per pass-A block
#define BCAP 6144     // LDS csr-window capacity per bucket (mean ~4096, sd ~64)

// RTNE float -> bf16
__device__ __forceinline__ unsigned short f2bf(float f) {
  uint u = __float_as_uint(f);
  u += 0x7fffu + ((u >> 16) & 1u);
  return (unsigned short)(u >> 16);
}
__device__ __forceinline__ float bfval(unsigned short b) {
  return __uint_as_float((uint)b << 16);
}
__device__ __forceinline__ uint pack2(float lo, float hi) {
  return (uint)f2bf(lo) | ((uint)f2bf(hi) << 16);
}
__device__ __forceinline__ float unpack_lo(uint u) { return __uint_as_float(u << 16); }
__device__ __forceinline__ float unpack_hi(uint u) { return __uint_as_float(u & 0xffff0000u); }

// ---- degree histogram + row-start scan ------------------------------------

__global__ __launch_bounds__(256) void k_hist(const int* __restrict__ dst,
                                              int* __restrict__ counts, int E) {
  int e = blockIdx.x * 256 + threadIdx.x;
  if (e < E) atomicAdd(&counts[dst[e]], 1);
}

__global__ __launch_bounds__(256) void k_scan1(const int* __restrict__ counts,
                                               int* __restrict__ excl,
                                               int* __restrict__ bsums, int N) {
  __shared__ int tmp[256];
  int i = blockIdx.x * 256 + threadIdx.x;
  int v = (i < N) ? counts[i] : 0;
  tmp[threadIdx.x] = v;
  __syncthreads();
  for (int off = 1; off < 256; off <<= 1) {
    int t = (threadIdx.x >= off) ? tmp[threadIdx.x - off] : 0;
    __syncthreads();
    tmp[threadIdx.x] += t;
    __syncthreads();
  }
  if (i < N) excl[i] = tmp[threadIdx.x] - v;
  if (threadIdx.x == 255) bsums[blockIdx.x] = tmp[255];
}

__global__ __launch_bounds__(512) void k_scan2(int* __restrict__ bsums, int nb) {
  __shared__ int tmp[512];
  int v = (threadIdx.x < nb) ? bsums[threadIdx.x] : 0;
  tmp[threadIdx.x] = v;
  __syncthreads();
  for (int off = 1; off < 512; off <<= 1) {
    int t = (threadIdx.x >= off) ? tmp[threadIdx.x - off] : 0;
    __syncthreads();
    tmp[threadIdx.x] += t;
    __syncthreads();
  }
  if (threadIdx.x < nb) bsums[threadIdx.x] = tmp[threadIdx.x] - v;
}

__global__ __launch_bounds__(256) void k_scan3(int* __restrict__ excl,
                                               const int* __restrict__ bsums, int N) {
  int i = blockIdx.x * 256 + threadIdx.x;
  if (i < N) excl[i] += bsums[blockIdx.x];
}

// ---- bucket cursor init: gbcur[b] = csr-space start of bucket b -----------

__global__ __launch_bounds__(256) void k_binit(const int* __restrict__ rowst,
                                               int* __restrict__ gbcur, int nb) {
  int b = blockIdx.x * 256 + threadIdx.x;
  if (b < nb) gbcur[b] = rowst[b << NBSHIFT];
}

// ---- Pass A: counting-sort edges into bucket-grouped bed[] ----------------
// Block-local histogram + LDS scan + LDS-staged grouping => coalesced runs
// out to bed. One global atomic per (block, bucket).

__global__ __launch_bounds__(256) void k_passA(const int* __restrict__ src,
                                               const int* __restrict__ dst,
                                               int* __restrict__ gbcur,
                                               int2* __restrict__ bed, int E) {
  __shared__ int bcnt[512];   // original per-bucket counts
  __shared__ int lbase[512];  // inclusive scan of counts
  __shared__ int bbase[512];  // global base per bucket
  __shared__ int lcur[512];   // staging cursor
  __shared__ int2 sbed[ACHUNK];
  int tid = threadIdx.x;
  int c0 = blockIdx.x * ACHUNK;
  int cend = min(c0 + ACHUNK, E);
  int total = cend - c0;
  for (int i = tid; i < 512; i += 256) bcnt[i] = 0;
  __syncthreads();
  for (int e = c0 + tid; e < cend; e += 256)
    atomicAdd(&bcnt[dst[e] >> NBSHIFT], 1);
  __syncthreads();
  for (int i = tid; i < 512; i += 256) lbase[i] = bcnt[i];
  __syncthreads();
  for (int off = 1; off < 512; off <<= 1) {
    int i0 = tid, i1 = tid + 256;
    int v0 = (i0 >= off) ? lbase[i0 - off] : 0;
    int v1 = (i1 >= off) ? lbase[i1 - off] : 0;
    __syncthreads();
    lbase[i0] += v0;
    lbase[i1] += v1;
    __syncthreads();
  }
  for (int i = tid; i < 512; i += 256) {
    int c = bcnt[i];
    bbase[i] = (c > 0) ? atomicAdd(&gbcur[i], c) : 0;
    lcur[i] = 0;
  }
  __syncthreads();
  for (int e = c0 + tid; e < cend; e += 256) {
    int s = src[e], d = dst[e];
    int b = d >> NBSHIFT;
    int lp = atomicAdd(&lcur[b], 1);
    sbed[lbase[b] - bcnt[b] + lp] = make_int2(s, d);
  }
  __syncthreads();
  for (int j = tid; j < total; j += 256) {
    int2 pr = sbed[j];
    int b = pr.y >> NBSHIFT;
    bed[bbase[b] + (j - (lbase[b] - bcnt[b]))] = pr;
  }
}

// ---- Pass B: one block per bucket; LDS-staged csr window ------------------

__global__ __launch_bounds__(256) void k_passB(const int2* __restrict__ bed,
                                               const int* __restrict__ rowst,
                                               int* __restrict__ csr, int N, int E) {
  __shared__ int lcur[256];
  __shared__ int scsr[BCAP];
  int b = blockIdx.x;
  int n0 = b << NBSHIFT;
  int n1 = min(n0 + 256, N);
  int e0 = rowst[n0];
  int e1 = (n1 < N) ? rowst[n1] : E;
  int sz = e1 - e0;
  int tid = threadIdx.x;
  lcur[tid] = (n0 + tid < n1) ? (rowst[n0 + tid] - e0) : 0;
  __syncthreads();
  if (sz <= BCAP) {
    for (int e = e0 + tid; e < e1; e += 256) {
      int2 pr = bed[e];
      int p = atomicAdd(&lcur[pr.y - n0], 1);
      scsr[p] = pr.x;
    }
    __syncthreads();
    for (int j = tid; j < sz; j += 256) csr[e0 + j] = scsr[j];
  } else {  // statistical overflow fallback (correct, slower)
    for (int e = e0 + tid; e < e1; e += 256) {
      int2 pr = bed[e];
      int p = atomicAdd(&lcur[pr.y - n0], 1);
      csr[e0 + p] = pr.x;
    }
  }
}

// ---- Prep: x fp32 [N][64] -> packed bf16 uint [N][32] ---------------------

__global__ __launch_bounds__(256) void k_prep(const float* __restrict__ x,
                                              uint* __restrict__ xb, int total) {
  int i = blockIdx.x * 256 + threadIdx.x;
  if (i < total) {
    float2 v = ((const float2*)x)[i];
    xb[i] = pack2(v.x, v.y);
  }
}

// ---- Aggregation layer 0: lane = one bf16 feature (2 B) -------------------
// Indices loaded lane-parallel (one coalesced load per 64 edges), rows
// gathered 8-deep independent.

__global__ __launch_bounds__(256) void k_agg0b(const unsigned short* __restrict__ xb,
                                               const int* __restrict__ rowst,
                                               const int* __restrict__ deg,
                                               const int* __restrict__ csr,
                                               unsigned short* __restrict__ agg, int N) {
  int lane = threadIdx.x & 63;
  int wid = (blockIdx.x * 256 + threadIdx.x) >> 6;
  int nw = (gridDim.x * 256) >> 6;
  for (int n = wid; n < N; n += nw) {
    int rs = rowst[n], d = deg[n];
    float m = -INFINITY;
    for (int base = 0; base < d; base += 64) {
      int cnt = min(d - base, 64);
      int idx = (lane < cnt) ? csr[rs + base + lane] : 0;
      int j = 0;
      for (; j + 8 <= cnt; j += 8) {
        float v0 = bfval(xb[(size_t)__shfl(idx, j + 0) * 64 + lane]);
        float v1 = bfval(xb[(size_t)__shfl(idx, j + 1) * 64 + lane]);
        float v2 = bfval(xb[(size_t)__shfl(idx, j + 2) * 64 + lane]);
        float v3 = bfval(xb[(size_t)__shfl(idx, j + 3) * 64 + lane]);
        float v4 = bfval(xb[(size_t)__shfl(idx, j + 4) * 64 + lane]);
        float v5 = bfval(xb[(size_t)__shfl(idx, j + 5) * 64 + lane]);
        float v6 = bfval(xb[(size_t)__shfl(idx, j + 6) * 64 + lane]);
        float v7 = bfval(xb[(size_t)__shfl(idx, j + 7) * 64 + lane]);
        m = fmaxf(m, fmaxf(fmaxf(fmaxf(v0, v1), fmaxf(v2, v3)),
                           fmaxf(fmaxf(v4, v5), fmaxf(v6, v7))));
      }
      for (; j < cnt; j++)
        m = fmaxf(m, bfval(xb[(size_t)__shfl(idx, j) * 64 + lane]));
    }
    agg[(size_t)n * 64 + lane] =
        (d > 0) ? (unsigned short)(__float_as_uint(m) >> 16) : (unsigned short)0;
  }
}

// ---- Aggregation layer 1: lane = packed bf16 pair (4 B) -------------------

__global__ __launch_bounds__(256) void k_agg1(const uint* __restrict__ h,
                                              const int* __restrict__ rowst,
                                              const int* __restrict__ deg,
                                              const int* __restrict__ csr,
                                              uint* __restrict__ agg, int N) {
  int lane = threadIdx.x & 63;
  int wid = (blockIdx.x * 256 + threadIdx.x) >> 6;
  int nw = (gridDim.x * 256) >> 6;
  for (int n = wid; n < N; n += nw) {
    int rs = rowst[n], d = deg[n];
    float mlo = -INFINITY, mhi = -INFINITY;
    for (int base = 0; base < d; base += 64) {
      int cnt = min(d - base, 64);
      int idx = (lane < cnt) ? csr[rs + base + lane] : 0;
      int j = 0;
      for (; j + 8 <= cnt; j += 8) {
        uint u0 = h[(size_t)__shfl(idx, j + 0) * 64 + lane];
        uint u1 = h[(size_t)__shfl(idx, j + 1) * 64 + lane];
        uint u2 = h[(size_t)__shfl(idx, j + 2) * 64 + lane];
        uint u3 = h[(size_t)__shfl(idx, j + 3) * 64 + lane];
        uint u4 = h[(size_t)__shfl(idx, j + 4) * 64 + lane];
        uint u5 = h[(size_t)__shfl(idx, j + 5) * 64 + lane];
        uint u6 = h[(size_t)__shfl(idx, j + 6) * 64 + lane];
        uint u7 = h[(size_t)__shfl(idx, j + 7) * 64 + lane];
        mlo = fmaxf(mlo, fmaxf(fmaxf(fmaxf(unpack_lo(u0), unpack_lo(u1)),
                                     fmaxf(unpack_lo(u2), unpack_lo(u3))),
                               fmaxf(fmaxf(unpack_lo(u4), unpack_lo(u5)),
                                     fmaxf(unpack_lo(u6), unpack_lo(u7)))));
        mhi = fmaxf(mhi, fmaxf(fmaxf(fmaxf(unpack_hi(u0), unpack_hi(u1)),
                                     fmaxf(unpack_hi(u2), unpack_hi(u3))),
                               fmaxf(fmaxf(unpack_hi(u4), unpack_hi(u5)),
                                     fmaxf(unpack_hi(u6), unpack_hi(u7)))));
      }
      for (; j < cnt; j++) {
        uint u = h[(size_t)__shfl(idx, j) * 64 + lane];
        mlo = fmaxf(mlo, unpack_lo(u));
        mhi = fmaxf(mhi, unpack_hi(u));
      }
    }
    uint packed = (__float_as_uint(mhi) & 0xffff0000u) | (__float_as_uint(mlo) >> 16);
    agg[(size_t)n * 64 + lane] = (d > 0) ? packed : 0u;
  }
}

// ---- Layer 0: h0 = LNrelu([agg0|x] @ [Wl0|Wr0]^T + bl0) -------------------

__global__ __launch_bounds__(256) void k_lin0(
    const uint* __restrict__ agg,  // N x 32 uints (bf16 [N][64])
    const uint* __restrict__ xb,   // N x 32 uints
    const float* __restrict__ Wl, const float* __restrict__ bl,
    const float* __restrict__ Wr, const float* __restrict__ g,
    const float* __restrict__ be, unsigned short* __restrict__ hout, int N) {
  __shared__ uint4 sB[4096];  // 64 KB: [ks 0..7][jt 0..7][lane 0..63]
  for (int e = threadIdx.x; e < 4096; e += 256) {
    int lane = e & 63, jt = (e >> 6) & 7, ks = e >> 9;
    int m = lane & 15, q = lane >> 4;
    int j = jt * 16 + m;
    int half = ks >> 2;             // 0 = hi, 1 = lo
    int kk = (ks & 3) * 32 + q * 8; // 0..120
    const float* srcr = (kk < 64) ? (Wl + (size_t)j * 64 + kk)
                                  : (Wr + (size_t)j * 64 + (kk - 64));
    float4 w0 = ((const float4*)srcr)[0];
    float4 w1 = ((const float4*)srcr)[1];
    float v[8] = {w0.x, w0.y, w0.z, w0.w, w1.x, w1.y, w1.z, w1.w};
    unsigned short b16[8];
#pragma unroll
    for (int i = 0; i < 8; i++) {
      unsigned short hi = f2bf(v[i]);
      b16[i] = half ? f2bf(v[i] - bfval(hi)) : hi;
    }
    uint4 p;
    p.x = (uint)b16[0] | ((uint)b16[1] << 16);
    p.y = (uint)b16[2] | ((uint)b16[3] << 16);
    p.z = (uint)b16[4] | ((uint)b16[5] << 16);
    p.w = (uint)b16[6] | ((uint)b16[7] << 16);
    sB[e] = p;
  }
  __syncthreads();

  int lane = threadIdx.x & 63, m = lane & 15, q = lane >> 4;
  int w = (blockIdx.x * 256 + threadIdx.x) >> 6;
  int nw = (gridDim.x * 256) >> 6;
  int pairs = (N + 31) / 32;
  float blv[8], gv[8], bev[8];
#pragma unroll
  for (int jt = 0; jt < 8; jt++) {
    blv[jt] = bl[jt * 16 + m];
    gv[jt] = g[jt * 16 + m];
    bev[jt] = be[jt * 16 + m];
  }
  for (int p = w; p < pairs; p += nw) {
    int b0 = p * 32;
    short8 a[2][4];
#pragma unroll
    for (int t = 0; t < 2; t++) {
      int row = b0 + t * 16 + m;
      const uint* r0 = agg + (size_t)row * 32;
      const uint* r1 = xb + (size_t)row * 32;
#pragma unroll
      for (int ks = 0; ks < 4; ks++) {
        const uint* base = (ks < 2) ? r0 : r1;
        a[t][ks] = __builtin_bit_cast(short8, *(const uint4*)(base + (ks & 1) * 16 + q * 4));
      }
    }
    f32x4 acc[2][8];
#pragma unroll
    for (int t = 0; t < 2; t++)
#pragma unroll
      for (int jt = 0; jt < 8; jt++) acc[t][jt] = {0.f, 0.f, 0.f, 0.f};
#pragma unroll
    for (int ks = 0; ks < 8; ks++) {
#pragma unroll
      for (int jt = 0; jt < 8; jt++) {
        short8 b = __builtin_bit_cast(short8, sB[(ks * 8 + jt) * 64 + lane]);
        acc[0][jt] = __builtin_amdgcn_mfma_f32_16x16x32_bf16(a[0][ks & 3], b, acc[0][jt], 0, 0, 0);
        acc[1][jt] = __builtin_amdgcn_mfma_f32_16x16x32_bf16(a[1][ks & 3], b, acc[1][jt], 0, 0, 0);
      }
    }
#pragma unroll
    for (int t = 0; t < 2; t++) {
      float s1[4] = {0.f, 0.f, 0.f, 0.f}, s2[4] = {0.f, 0.f, 0.f, 0.f};
#pragma unroll
      for (int jt = 0; jt < 8; jt++) {
        float bb = blv[jt];
#pragma unroll
        for (int r = 0; r < 4; r++) {
          float v = acc[t][jt][r] + bb;
          s1[r] += v;
          s2[r] += v * v;
        }
      }
#pragma unroll
      for (int off = 1; off < 16; off <<= 1) {
#pragma unroll
        for (int r = 0; r < 4; r++) {
          s1[r] += __shfl_xor(s1[r], off);
          s2[r] += __shfl_xor(s2[r], off);
        }
      }
      float mu[4], rstd[4];
#pragma unroll
      for (int r = 0; r < 4; r++) {
        mu[r] = s1[r] * (1.0f / 128.0f);
        float var = s2[r] * (1.0f / 128.0f) - mu[r] * mu[r];
        rstd[r] = rsqrtf(var + 1e-5f);
      }
      int nodeb = b0 + t * 16 + q * 4;
#pragma unroll
      for (int jt = 0; jt < 8; jt++) {
        float bb = blv[jt];
#pragma unroll
        for (int r = 0; r < 4; r++) {
          int node = nodeb + r;
          if (node < N) {
            float v = acc[t][jt][r] + bb;
            float o = fmaxf((v - mu[r]) * rstd[r] * gv[jt] + bev[jt], 0.0f);
            hout[(size_t)node * 128 + jt * 16 + m] = f2bf(o);
          }
        }
      }
    }
  }
}

// ---- Layer 1: h1 = LNrelu([agg1|h0] @ [Wl1|Wr1]^T + bl1), in-place --------

__global__ __launch_bounds__(256) void k_lin1(
    uint* agg,                     // N x 64 uints; becomes h1 (bf16 [N][128])
    const uint* __restrict__ h0,   // N x 64 uints
    const float* __restrict__ Wl, const float* __restrict__ bl,
    const float* __restrict__ Wr, const float* __restrict__ g,
    const float* __restrict__ be, int N) {
  __shared__ uint4 sB[4096];  // 64 KB
  for (int e = threadIdx.x; e < 4096; e += 256) {
    int lane = e & 63, jt = (e >> 6) & 7, ks = e >> 9;
    int m = lane & 15, q = lane >> 4;
    int j = jt * 16 + m;
    int k0 = ks * 32 + q * 8;  // 0..248
    const float* srcr = (k0 < 128) ? (Wl + (size_t)j * 128 + k0)
                                   : (Wr + (size_t)j * 128 + (k0 - 128));
    float4 w0 = ((const float4*)srcr)[0];
    float4 w1 = ((const float4*)srcr)[1];
    uint4 p;
    p.x = pack2(w0.x, w0.y);
    p.y = pack2(w0.z, w0.w);
    p.z = pack2(w1.x, w1.y);
    p.w = pack2(w1.z, w1.w);
    sB[e] = p;
  }
  __syncthreads();

  int lane = threadIdx.x & 63, m = lane & 15, q = lane >> 4;
  int w = (blockIdx.x * 256 + threadIdx.x) >> 6;
  int nw = (gridDim.x * 256) >> 6;
  int pairs = (N + 31) / 32;
  float blv[8], gv[8], bev[8];
#pragma unroll
  for (int jt = 0; jt < 8; jt++) {
    blv[jt] = bl[jt * 16 + m];
    gv[jt] = g[jt * 16 + m];
    bev[jt] = be[jt * 16 + m];
  }
  unsigned short* hout = (unsigned short*)agg;
  for (int p = w; p < pairs; p += nw) {
    int b0 = p * 32;
    short8 a[2][8];
#pragma unroll
    for (int t = 0; t < 2; t++) {
      int row = b0 + t * 16 + m;
      const uint* r0 = agg + (size_t)row * 64;
      const uint* r1 = h0 + (size_t)row * 64;
#pragma unroll
      for (int ks = 0; ks < 8; ks++) {
        const uint* base = (ks < 4) ? r0 : r1;
        a[t][ks] = __builtin_bit_cast(short8, *(const uint4*)(base + (ks & 3) * 16 + q * 4));
      }
    }
    f32x4 acc[2][8];
#pragma unroll
    for (int t = 0; t < 2; t++)
#pragma unroll
      for (int jt = 0; jt < 8; jt++) acc[t][jt] = {0.f, 0.f, 0.f, 0.f};
#pragma unroll
    for (int ks = 0; ks < 8; ks++) {
#pragma unroll
      for (int jt = 0; jt < 8; jt++) {
        short8 b = __builtin_bit_cast(short8, sB[(ks * 8 + jt) * 64 + lane]);
        acc[0][jt] = __builtin_amdgcn_mfma_f32_16x16x32_bf16(a[0][ks], b, acc[0][jt], 0, 0, 0);
        acc[1][jt] = __builtin_amdgcn_mfma_f32_16x16x32_bf16(a[1][ks], b, acc[1][jt], 0, 0, 0);
      }
    }
#pragma unroll
    for (int t = 0; t < 2; t++) {
      float s1[4] = {0.f, 0.f, 0.f, 0.f}, s2[4] = {0.f, 0.f, 0.f, 0.f};
#pragma unroll
      for (int jt = 0; jt < 8; jt++) {
        float bb = blv[jt];
#pragma unroll
        for (int r = 0; r < 4; r++) {
          float v = acc[t][jt][r] + bb;
          s1[r] += v;
          s2[r] += v * v;
        }
      }
#pragma unroll
      for (int off = 1; off < 16; off <<= 1) {
#pragma unroll
        for (int r = 0; r < 4; r++) {
          s1[r] += __shfl_xor(s1[r], off);
          s2[r] += __shfl_xor(s2[r], off);
        }
      }
      float mu[4], rstd[4];
#pragma unroll
      for (int r = 0; r < 4; r++) {
        mu[r] = s1[r] * (1.0f / 128.0f);
        float var = s2[r] * (1.0f / 128.0f) - mu[r] * mu[r];
        rstd[r] = rsqrtf(var + 1e-5f);
      }
      int nodeb = b0 + t * 16 + q * 4;
#pragma unroll
      for (int jt = 0; jt < 8; jt++) {
        float bb = blv[jt];
#pragma unroll
        for (int r = 0; r < 4; r++) {
          int node = nodeb + r;
          if (node < N) {
            float v = acc[t][jt][r] + bb;
            float o = fmaxf((v - mu[r]) * rstd[r] * gv[jt] + bev[jt], 0.0f);
            hout[(size_t)node * 128 + jt * 16 + m] = f2bf(o);
          }
        }
      }
    }
  }
}

// ---- MLP head: out = sigmoid(relu(h1@W1.T+b1) @ W2.T + b2) ----------------

__global__ __launch_bounds__(256) void k_mlp(const uint* __restrict__ h1,
                                             const float* __restrict__ W1,
                                             const float* __restrict__ b1,
                                             const float* __restrict__ W2,
                                             const float* __restrict__ b2,
                                             float* __restrict__ out, int N) {
  __shared__ uint4 sB[1024];  // 16 KB: [ks 0..3][jt 0..3][lane]
  for (int e = threadIdx.x; e < 1024; e += 256) {
    int lane = e & 63, jt = (e >> 6) & 3, ks = e >> 8;
    int m = lane & 15, q = lane >> 4;
    int j = jt * 16 + m;          // 0..63
    int k0 = ks * 32 + q * 8;     // 0..120
    const float* srcr = W1 + (size_t)j * 128 + k0;
    float4 w0 = ((const float4*)srcr)[0];
    float4 w1 = ((const float4*)srcr)[1];
    uint4 p;
    p.x = pack2(w0.x, w0.y);
    p.y = pack2(w0.z, w0.w);
    p.z = pack2(w1.x, w1.y);
    p.w = pack2(w1.z, w1.w);
    sB[e] = p;
  }
  __syncthreads();

  int lane = threadIdx.x & 63, m = lane & 15, q = lane >> 4;
  int w = (blockIdx.x * 256 + threadIdx.x) >> 6;
  int nw = (gridDim.x * 256) >> 6;
  int tiles = (N + 15) / 16;
  float b1v[4], w2v[4];
#pragma unroll
  for (int jt = 0; jt < 4; jt++) {
    b1v[jt] = b1[jt * 16 + m];
    w2v[jt] = W2[jt * 16 + m];
  }
  float b2v = b2[0];
  for (int tl = w; tl < tiles; tl += nw) {
    int b0 = tl * 16;
    int row = b0 + m;
    const uint* r0 = h1 + (size_t)row * 64;
    short8 a[4];
#pragma unroll
    for (int ks = 0; ks < 4; ks++)
      a[ks] = __builtin_bit_cast(short8, *(const uint4*)(r0 + ks * 16 + q * 4));
    f32x4 acc[4];
#pragma unroll
    for (int jt = 0; jt < 4; jt++) acc[jt] = {0.f, 0.f, 0.f, 0.f};
#pragma unroll
    for (int ks = 0; ks < 4; ks++) {
#pragma unroll
      for (int jt = 0; jt < 4; jt++) {
        short8 b = __builtin_bit_cast(short8, sB[(ks * 4 + jt) * 64 + lane]);
        acc[jt] = __builtin_amdgcn_mfma_f32_16x16x32_bf16(a[ks], b, acc[jt], 0, 0, 0);
      }
    }
    float part[4] = {0.f, 0.f, 0.f, 0.f};
#pragma unroll
    for (int jt = 0; jt < 4; jt++) {
#pragma unroll
      for (int r = 0; r < 4; r++)
        part[r] += fmaxf(acc[jt][r] + b1v[jt], 0.0f) * w2v[jt];
    }
#pragma unroll
    for (int off = 1; off < 16; off <<= 1) {
#pragma unroll
      for (int r = 0; r < 4; r++) part[r] += __shfl_xor(part[r], off);
    }
    if (m == 0) {
#pragma unroll
      for (int r = 0; r < 4; r++) {
        int node = b0 + q * 4 + r;
        if (node < N) out[node] = 1.0f / (1.0f + expf(-(part[r] + b2v)));
      }
    }
  }
}

// ---------------------------------------------------------------------------

extern "C" void kernel_launch(void* const* d_in, const int* in_sizes, int n_in,
                              void* d_out, int out_size, void* d_ws, size_t ws_size,
                              hipStream_t stream) {
  const float* x = (const float*)d_in[0];
  const int* ei = (const int*)d_in[1];
  const float* Wl0 = (const float*)d_in[2];
  const float* bl0 = (const float*)d_in[3];
  const float* Wr0 = (const float*)d_in[4];
  const float* g0 = (const float*)d_in[5];
  const float* be0 = (const float*)d_in[6];
  const float* Wl1 = (const float*)d_in[7];
  const float* bl1 = (const float*)d_in[8];
  const float* Wr1 = (const float*)d_in[9];
  const float* g1 = (const float*)d_in[10];
  const float* be1 = (const float*)d_in[11];
  const float* W1 = (const float*)d_in[12];
  const float* b1 = (const float*)d_in[13];
  const float* W2 = (const float*)d_in[14];
  const float* b2 = (const float*)d_in[15];
  float* out = (float*)d_out;

  const int N = in_sizes[0] / 64;
  const int E = in_sizes[1] / 2;
  const int* src = ei;
  const int* dst = ei + E;
  const int nb = ceil_div(N, 1 << NBSHIFT);

  // Workspace (~58.8 MB peak):
  //   misc + csr (6.4 MB) + regionX (25.6 MB) + h0buf (25.6 MB)
  // h0buf timeline: bed (12.8 MB, pass A/B) -> h0 (k_lin0 onward).
  // regionX timeline: [xb | agg0b] -> agg1 -> h1 (in-place).
  char* ws = (char*)d_ws;
  size_t off = 0;
  auto alloc = [&](size_t bytes) -> void* {
    void* p = ws + off;
    off = (off + bytes + 255) & ~(size_t)255;
    return p;
  };
  int* counts = (int*)alloc((size_t)N * 4);
  int* rowst = (int*)alloc((size_t)N * 4);
  int* gbcur = (int*)alloc(512 * 4);
  int* bsums = (int*)alloc(512 * 4);
  int* csr = (int*)alloc((size_t)E * 4);
  uint* regionX = (uint*)alloc((size_t)N * 64 * 4);  // 25.6 MB
  uint* h0buf = (uint*)alloc((size_t)N * 64 * 4);    // 25.6 MB

  uint* xb = regionX;                      // N x 32 uints
  uint* agg0b = regionX + (size_t)N * 32;  // N x 32 uints
  uint* agg1 = regionX;                    // N x 64 uints (over dead xb/agg0b)
  int2* bed = (int2*)h0buf;                // E x 8 B, dead before k_lin0

  hipMemsetAsync(counts, 0, (size_t)N * 4, stream);

  int nb1 = ceil_div(N, 256);
  k_prep<<<ceil_div(N * 32, 256), 256, 0, stream>>>(x, xb, N * 32);
  k_hist<<<ceil_div(E, 256), 256, 0, stream>>>(dst, counts, E);
  k_scan1<<<nb1, 256, 0, stream>>>(counts, rowst, bsums, N);
  k_scan2<<<1, 512, 0, stream>>>(bsums, nb1);
  k_scan3<<<nb1, 256, 0, stream>>>(rowst, bsums, N);
  k_binit<<<ceil_div(nb, 256), 256, 0, stream>>>(rowst, gbcur, nb);
  k_passA<<<ceil_div(E, ACHUNK), 256, 0, stream>>>(src, dst, gbcur, bed, E);
  k_passB<<<nb, 256, 0, stream>>>(bed, rowst, csr, N, E);

  k_agg0b<<<2048, 256, 0, stream>>>((const unsigned short*)xb, rowst, counts, csr,
                                    (unsigned short*)agg0b, N);
  k_lin0<<<512, 256, 0, stream>>>(agg0b, xb, Wl0, bl0, Wr0, g0, be0,
                                  (unsigned short*)h0buf, N);
  k_agg1<<<2048, 256, 0, stream>>>(h0buf, rowst, counts, csr, agg1, N);
  k_lin1<<<512, 256, 0, stream>>>(agg1, h0buf, Wl1, bl1, Wr1, g1, be1, N);
  k_mlp<<<512, 256, 0, stream>>>(agg1, W1, b1, W2, b2, out, N);
}

// Round 5
// 354.051 us; speedup vs baseline: 3.5513x; 1.1668x over previous
//
#include <hip/hip_runtime.h>
#include <math.h>

// ---------------------------------------------------------------------------
// GraphSAGE (max aggr) x2 + LN + ReLU + MLP head + sigmoid.
// CSR build via 2-level LDS-staged counting sort with NO N-wide global
// atomics: round-4's k_hist (1.6M random atomicAdds on counts[]) produced
// 50 MB of HBM writes via cross-XCD line ping-pong. Per-node degrees and
// row starts are now computed inside the per-bucket pass-B kernel (each
// block owns a disjoint 256-node range -> LDS counters only).
// Gather-max aggregation with lane-parallel index loads -> MFMA GEMM linear
// layers with fused LN/ReLU/sigmoid epilogues.
// Workspace ~58.8 MB: bed (12.8 MB) aliases the h0 buffer (dead until
// k_lin0), h1 overwrites agg1 in-place.
// ---------------------------------------------------------------------------

static inline int ceil_div(int a, int b) { return (a + b - 1) / b; }

typedef unsigned int uint;
typedef __attribute__((ext_vector_type(8))) short short8;
typedef __attribute__((ext_vector_type(4))) float f32x4;

#define NBSHIFT 8     // bucket = 256 dst nodes
#define ACHUNK 4096   // edges per pass-A block
#define BCAP 6144     // LDS csr-window capacity per bucket (mean ~4096, sd ~64)

// RTNE float -> bf16
__device__ __forceinline__ unsigned short f2bf(float f) {
  uint u = __float_as_uint(f);
  u += 0x7fffu + ((u >> 16) & 1u);
  return (unsigned short)(u >> 16);
}
__device__ __forceinline__ float bfval(unsigned short b) {
  return __uint_as_float((uint)b << 16);
}
__device__ __forceinline__ uint pack2(float lo, float hi) {
  return (uint)f2bf(lo) | ((uint)f2bf(hi) << 16);
}
__device__ __forceinline__ float unpack_lo(uint u) { return __uint_as_float(u << 16); }
__device__ __forceinline__ float unpack_hi(uint u) { return __uint_as_float(u & 0xffff0000u); }

// ---- bucket histogram (LDS-aggregated, ~200K global atomics total) --------

__global__ __launch_bounds__(256) void k_bhist(const int* __restrict__ dst,
                                               int* __restrict__ gbtot, int E) {
  __shared__ int bcnt[512];
  int tid = threadIdx.x;
  for (int i = tid; i < 512; i += 256) bcnt[i] = 0;
  __syncthreads();
  int c0 = blockIdx.x * ACHUNK;
  int cend = min(c0 + ACHUNK, E);
  for (int e = c0 + tid; e < cend; e += 256)
    atomicAdd(&bcnt[dst[e] >> NBSHIFT], 1);
  __syncthreads();
  for (int i = tid; i < 512; i += 256) {
    int c = bcnt[i];
    if (c) atomicAdd(&gbtot[i], c);
  }
}

// ---- bucket scan: gbase = exclusive scan of gbtot; gbcur = copy -----------

__global__ __launch_bounds__(512) void k_bscan(const int* __restrict__ gbtot,
                                               int* __restrict__ gbase,
                                               int* __restrict__ gbcur) {
  __shared__ int tmp[512];
  int v = gbtot[threadIdx.x];
  tmp[threadIdx.x] = v;
  __syncthreads();
  for (int off = 1; off < 512; off <<= 1) {
    int t = (threadIdx.x >= off) ? tmp[threadIdx.x - off] : 0;
    __syncthreads();
    tmp[threadIdx.x] += t;
    __syncthreads();
  }
  int ex = tmp[threadIdx.x] - v;
  gbase[threadIdx.x] = ex;
  gbcur[threadIdx.x] = ex;
}

// ---- Pass A: counting-sort edges into bucket-grouped bed[] ----------------

__global__ __launch_bounds__(256) void k_passA(const int* __restrict__ src,
                                               const int* __restrict__ dst,
                                               int* __restrict__ gbcur,
                                               int2* __restrict__ bed, int E) {
  __shared__ int bcnt[512];   // original per-bucket counts
  __shared__ int lbase[512];  // inclusive scan of counts
  __shared__ int bbase[512];  // global base per bucket
  __shared__ int lcur[512];   // staging cursor
  __shared__ int2 sbed[ACHUNK];
  int tid = threadIdx.x;
  int c0 = blockIdx.x * ACHUNK;
  int cend = min(c0 + ACHUNK, E);
  int total = cend - c0;
  for (int i = tid; i < 512; i += 256) bcnt[i] = 0;
  __syncthreads();
  for (int e = c0 + tid; e < cend; e += 256)
    atomicAdd(&bcnt[dst[e] >> NBSHIFT], 1);
  __syncthreads();
  for (int i = tid; i < 512; i += 256) lbase[i] = bcnt[i];
  __syncthreads();
  for (int off = 1; off < 512; off <<= 1) {
    int i0 = tid, i1 = tid + 256;
    int v0 = (i0 >= off) ? lbase[i0 - off] : 0;
    int v1 = (i1 >= off) ? lbase[i1 - off] : 0;
    __syncthreads();
    lbase[i0] += v0;
    lbase[i1] += v1;
    __syncthreads();
  }
  for (int i = tid; i < 512; i += 256) {
    int c = bcnt[i];
    bbase[i] = (c > 0) ? atomicAdd(&gbcur[i], c) : 0;
    lcur[i] = 0;
  }
  __syncthreads();
  for (int e = c0 + tid; e < cend; e += 256) {
    int s = src[e], d = dst[e];
    int b = d >> NBSHIFT;
    int lp = atomicAdd(&lcur[b], 1);
    sbed[lbase[b] - bcnt[b] + lp] = make_int2(s, d);
  }
  __syncthreads();
  for (int j = tid; j < total; j += 256) {
    int2 pr = sbed[j];
    int b = pr.y >> NBSHIFT;
    bed[bbase[b] + (j - (lbase[b] - bcnt[b]))] = pr;
  }
}

// ---- Pass B: one block per bucket. Computes per-node degree + row starts
// in LDS (no global atomics), writes counts/rowst coalesced, then scatters
// src into an LDS csr window and streams it out.

__global__ __launch_bounds__(256) void k_passB(const int2* __restrict__ bed,
                                               const int* __restrict__ gbase,
                                               int* __restrict__ counts,
                                               int* __restrict__ rowst,
                                               int* __restrict__ csr, int N, int E) {
  __shared__ int cnt[256];
  __shared__ int scn[256];
  __shared__ int lcur[256];
  __shared__ int scsr[BCAP];
  int b = blockIdx.x, tid = threadIdx.x;
  int n0 = b << NBSHIFT;
  int n1 = min(n0 + 256, N);
  int e0 = gbase[b];
  int e1 = (b + 1 < 512) ? gbase[b + 1] : E;  // gridDim = nb <= 391 < 512
  if (b + 1 == gridDim.x) e1 = E;
  int sz = e1 - e0;
  cnt[tid] = 0;
  __syncthreads();
  for (int e = e0 + tid; e < e1; e += 256)
    atomicAdd(&cnt[bed[e].y - n0], 1);
  __syncthreads();
  scn[tid] = cnt[tid];
  __syncthreads();
  for (int off = 1; off < 256; off <<= 1) {
    int t = (tid >= off) ? scn[tid - off] : 0;
    __syncthreads();
    scn[tid] += t;
    __syncthreads();
  }
  int ex = scn[tid] - cnt[tid];
  if (n0 + tid < n1) {
    counts[n0 + tid] = cnt[tid];
    rowst[n0 + tid] = e0 + ex;
  }
  lcur[tid] = ex;
  __syncthreads();
  if (sz <= BCAP) {
    for (int e = e0 + tid; e < e1; e += 256) {
      int2 pr = bed[e];
      int p = atomicAdd(&lcur[pr.y - n0], 1);
      scsr[p] = pr.x;
    }
    __syncthreads();
    for (int j = tid; j < sz; j += 256) csr[e0 + j] = scsr[j];
  } else {  // statistical overflow fallback (correct, slower)
    for (int e = e0 + tid; e < e1; e += 256) {
      int2 pr = bed[e];
      int p = atomicAdd(&lcur[pr.y - n0], 1);
      csr[e0 + p] = pr.x;
    }
  }
}

// ---- Prep: x fp32 [N][64] -> packed bf16 uint [N][32] ---------------------

__global__ __launch_bounds__(256) void k_prep(const float* __restrict__ x,
                                              uint* __restrict__ xb, int total) {
  int i = blockIdx.x * 256 + threadIdx.x;
  if (i < total) {
    float2 v = ((const float2*)x)[i];
    xb[i] = pack2(v.x, v.y);
  }
}

// ---- Aggregation layer 0: lane = one bf16 feature (2 B) -------------------

__global__ __launch_bounds__(256) void k_agg0b(const unsigned short* __restrict__ xb,
                                               const int* __restrict__ rowst,
                                               const int* __restrict__ deg,
                                               const int* __restrict__ csr,
                                               unsigned short* __restrict__ agg, int N) {
  int lane = threadIdx.x & 63;
  int wid = (blockIdx.x * 256 + threadIdx.x) >> 6;
  int nw = (gridDim.x * 256) >> 6;
  for (int n = wid; n < N; n += nw) {
    int rs = rowst[n], d = deg[n];
    float m = -INFINITY;
    for (int base = 0; base < d; base += 64) {
      int cnt = min(d - base, 64);
      int idx = (lane < cnt) ? csr[rs + base + lane] : 0;
      int j = 0;
      for (; j + 8 <= cnt; j += 8) {
        float v0 = bfval(xb[(size_t)__shfl(idx, j + 0) * 64 + lane]);
        float v1 = bfval(xb[(size_t)__shfl(idx, j + 1) * 64 + lane]);
        float v2 = bfval(xb[(size_t)__shfl(idx, j + 2) * 64 + lane]);
        float v3 = bfval(xb[(size_t)__shfl(idx, j + 3) * 64 + lane]);
        float v4 = bfval(xb[(size_t)__shfl(idx, j + 4) * 64 + lane]);
        float v5 = bfval(xb[(size_t)__shfl(idx, j + 5) * 64 + lane]);
        float v6 = bfval(xb[(size_t)__shfl(idx, j + 6) * 64 + lane]);
        float v7 = bfval(xb[(size_t)__shfl(idx, j + 7) * 64 + lane]);
        m = fmaxf(m, fmaxf(fmaxf(fmaxf(v0, v1), fmaxf(v2, v3)),
                           fmaxf(fmaxf(v4, v5), fmaxf(v6, v7))));
      }
      for (; j < cnt; j++)
        m = fmaxf(m, bfval(xb[(size_t)__shfl(idx, j) * 64 + lane]));
    }
    agg[(size_t)n * 64 + lane] =
        (d > 0) ? (unsigned short)(__float_as_uint(m) >> 16) : (unsigned short)0;
  }
}

// ---- Aggregation layer 1: lane = packed bf16 pair (4 B) -------------------

__global__ __launch_bounds__(256) void k_agg1(const uint* __restrict__ h,
                                              const int* __restrict__ rowst,
                                              const int* __restrict__ deg,
                                              const int* __restrict__ csr,
                                              uint* __restrict__ agg, int N) {
  int lane = threadIdx.x & 63;
  int wid = (blockIdx.x * 256 + threadIdx.x) >> 6;
  int nw = (gridDim.x * 256) >> 6;
  for (int n = wid; n < N; n += nw) {
    int rs = rowst[n], d = deg[n];
    float mlo = -INFINITY, mhi = -INFINITY;
    for (int base = 0; base < d; base += 64) {
      int cnt = min(d - base, 64);
      int idx = (lane < cnt) ? csr[rs + base + lane] : 0;
      int j = 0;
      for (; j + 8 <= cnt; j += 8) {
        uint u0 = h[(size_t)__shfl(idx, j + 0) * 64 + lane];
        uint u1 = h[(size_t)__shfl(idx, j + 1) * 64 + lane];
        uint u2 = h[(size_t)__shfl(idx, j + 2) * 64 + lane];
        uint u3 = h[(size_t)__shfl(idx, j + 3) * 64 + lane];
        uint u4 = h[(size_t)__shfl(idx, j + 4) * 64 + lane];
        uint u5 = h[(size_t)__shfl(idx, j + 5) * 64 + lane];
        uint u6 = h[(size_t)__shfl(idx, j + 6) * 64 + lane];
        uint u7 = h[(size_t)__shfl(idx, j + 7) * 64 + lane];
        mlo = fmaxf(mlo, fmaxf(fmaxf(fmaxf(unpack_lo(u0), unpack_lo(u1)),
                                     fmaxf(unpack_lo(u2), unpack_lo(u3))),
                               fmaxf(fmaxf(unpack_lo(u4), unpack_lo(u5)),
                                     fmaxf(unpack_lo(u6), unpack_lo(u7)))));
        mhi = fmaxf(mhi, fmaxf(fmaxf(fmaxf(unpack_hi(u0), unpack_hi(u1)),
                                     fmaxf(unpack_hi(u2), unpack_hi(u3))),
                               fmaxf(fmaxf(unpack_hi(u4), unpack_hi(u5)),
                                     fmaxf(unpack_hi(u6), unpack_hi(u7)))));
      }
      for (; j < cnt; j++) {
        uint u = h[(size_t)__shfl(idx, j) * 64 + lane];
        mlo = fmaxf(mlo, unpack_lo(u));
        mhi = fmaxf(mhi, unpack_hi(u));
      }
    }
    uint packed = (__float_as_uint(mhi) & 0xffff0000u) | (__float_as_uint(mlo) >> 16);
    agg[(size_t)n * 64 + lane] = (d > 0) ? packed : 0u;
  }
}

// ---- Layer 0: h0 = LNrelu([agg0|x] @ [Wl0|Wr0]^T + bl0) -------------------

__global__ __launch_bounds__(256) void k_lin0(
    const uint* __restrict__ agg,  // N x 32 uints (bf16 [N][64])
    const uint* __restrict__ xb,   // N x 32 uints
    const float* __restrict__ Wl, const float* __restrict__ bl,
    const float* __restrict__ Wr, const float* __restrict__ g,
    const float* __restrict__ be, unsigned short* __restrict__ hout, int N) {
  __shared__ uint4 sB[4096];  // 64 KB: [ks 0..7][jt 0..7][lane 0..63]
  for (int e = threadIdx.x; e < 4096; e += 256) {
    int lane = e & 63, jt = (e >> 6) & 7, ks = e >> 9;
    int m = lane & 15, q = lane >> 4;
    int j = jt * 16 + m;
    int half = ks >> 2;             // 0 = hi, 1 = lo
    int kk = (ks & 3) * 32 + q * 8; // 0..120
    const float* srcr = (kk < 64) ? (Wl + (size_t)j * 64 + kk)
                                  : (Wr + (size_t)j * 64 + (kk - 64));
    float4 w0 = ((const float4*)srcr)[0];
    float4 w1 = ((const float4*)srcr)[1];
    float v[8] = {w0.x, w0.y, w0.z, w0.w, w1.x, w1.y, w1.z, w1.w};
    unsigned short b16[8];
#pragma unroll
    for (int i = 0; i < 8; i++) {
      unsigned short hi = f2bf(v[i]);
      b16[i] = half ? f2bf(v[i] - bfval(hi)) : hi;
    }
    uint4 p;
    p.x = (uint)b16[0] | ((uint)b16[1] << 16);
    p.y = (uint)b16[2] | ((uint)b16[3] << 16);
    p.z = (uint)b16[4] | ((uint)b16[5] << 16);
    p.w = (uint)b16[6] | ((uint)b16[7] << 16);
    sB[e] = p;
  }
  __syncthreads();

  int lane = threadIdx.x & 63, m = lane & 15, q = lane >> 4;
  int w = (blockIdx.x * 256 + threadIdx.x) >> 6;
  int nw = (gridDim.x * 256) >> 6;
  int pairs = (N + 31) / 32;
  float blv[8], gv[8], bev[8];
#pragma unroll
  for (int jt = 0; jt < 8; jt++) {
    blv[jt] = bl[jt * 16 + m];
    gv[jt] = g[jt * 16 + m];
    bev[jt] = be[jt * 16 + m];
  }
  for (int p = w; p < pairs; p += nw) {
    int b0 = p * 32;
    short8 a[2][4];
#pragma unroll
    for (int t = 0; t < 2; t++) {
      int row = b0 + t * 16 + m;
      const uint* r0 = agg + (size_t)row * 32;
      const uint* r1 = xb + (size_t)row * 32;
#pragma unroll
      for (int ks = 0; ks < 4; ks++) {
        const uint* base = (ks < 2) ? r0 : r1;
        a[t][ks] = __builtin_bit_cast(short8, *(const uint4*)(base + (ks & 1) * 16 + q * 4));
      }
    }
    f32x4 acc[2][8];
#pragma unroll
    for (int t = 0; t < 2; t++)
#pragma unroll
      for (int jt = 0; jt < 8; jt++) acc[t][jt] = {0.f, 0.f, 0.f, 0.f};
#pragma unroll
    for (int ks = 0; ks < 8; ks++) {
#pragma unroll
      for (int jt = 0; jt < 8; jt++) {
        short8 b = __builtin_bit_cast(short8, sB[(ks * 8 + jt) * 64 + lane]);
        acc[0][jt] = __builtin_amdgcn_mfma_f32_16x16x32_bf16(a[0][ks & 3], b, acc[0][jt], 0, 0, 0);
        acc[1][jt] = __builtin_amdgcn_mfma_f32_16x16x32_bf16(a[1][ks & 3], b, acc[1][jt], 0, 0, 0);
      }
    }
#pragma unroll
    for (int t = 0; t < 2; t++) {
      float s1[4] = {0.f, 0.f, 0.f, 0.f}, s2[4] = {0.f, 0.f, 0.f, 0.f};
#pragma unroll
      for (int jt = 0; jt < 8; jt++) {
        float bb = blv[jt];
#pragma unroll
        for (int r = 0; r < 4; r++) {
          float v = acc[t][jt][r] + bb;
          s1[r] += v;
          s2[r] += v * v;
        }
      }
#pragma unroll
      for (int off = 1; off < 16; off <<= 1) {
#pragma unroll
        for (int r = 0; r < 4; r++) {
          s1[r] += __shfl_xor(s1[r], off);
          s2[r] += __shfl_xor(s2[r], off);
        }
      }
      float mu[4], rstd[4];
#pragma unroll
      for (int r = 0; r < 4; r++) {
        mu[r] = s1[r] * (1.0f / 128.0f);
        float var = s2[r] * (1.0f / 128.0f) - mu[r] * mu[r];
        rstd[r] = rsqrtf(var + 1e-5f);
      }
      int nodeb = b0 + t * 16 + q * 4;
#pragma unroll
      for (int jt = 0; jt < 8; jt++) {
        float bb = blv[jt];
#pragma unroll
        for (int r = 0; r < 4; r++) {
          int node = nodeb + r;
          if (node < N) {
            float v = acc[t][jt][r] + bb;
            float o = fmaxf((v - mu[r]) * rstd[r] * gv[jt] + bev[jt], 0.0f);
            hout[(size_t)node * 128 + jt * 16 + m] = f2bf(o);
          }
        }
      }
    }
  }
}

// ---- Layer 1: h1 = LNrelu([agg1|h0] @ [Wl1|Wr1]^T + bl1), in-place --------

__global__ __launch_bounds__(256) void k_lin1(
    uint* agg,                     // N x 64 uints; becomes h1 (bf16 [N][128])
    const uint* __restrict__ h0,   // N x 64 uints
    const float* __restrict__ Wl, const float* __restrict__ bl,
    const float* __restrict__ Wr, const float* __restrict__ g,
    const float* __restrict__ be, int N) {
  __shared__ uint4 sB[4096];  // 64 KB
  for (int e = threadIdx.x; e < 4096; e += 256) {
    int lane = e & 63, jt = (e >> 6) & 7, ks = e >> 9;
    int m = lane & 15, q = lane >> 4;
    int j = jt * 16 + m;
    int k0 = ks * 32 + q * 8;  // 0..248
    const float* srcr = (k0 < 128) ? (Wl + (size_t)j * 128 + k0)
                                   : (Wr + (size_t)j * 128 + (k0 - 128));
    float4 w0 = ((const float4*)srcr)[0];
    float4 w1 = ((const float4*)srcr)[1];
    uint4 p;
    p.x = pack2(w0.x, w0.y);
    p.y = pack2(w0.z, w0.w);
    p.z = pack2(w1.x, w1.y);
    p.w = pack2(w1.z, w1.w);
    sB[e] = p;
  }
  __syncthreads();

  int lane = threadIdx.x & 63, m = lane & 15, q = lane >> 4;
  int w = (blockIdx.x * 256 + threadIdx.x) >> 6;
  int nw = (gridDim.x * 256) >> 6;
  int pairs = (N + 31) / 32;
  float blv[8], gv[8], bev[8];
#pragma unroll
  for (int jt = 0; jt < 8; jt++) {
    blv[jt] = bl[jt * 16 + m];
    gv[jt] = g[jt * 16 + m];
    bev[jt] = be[jt * 16 + m];
  }
  unsigned short* hout = (unsigned short*)agg;
  for (int p = w; p < pairs; p += nw) {
    int b0 = p * 32;
    short8 a[2][8];
#pragma unroll
    for (int t = 0; t < 2; t++) {
      int row = b0 + t * 16 + m;
      const uint* r0 = agg + (size_t)row * 64;
      const uint* r1 = h0 + (size_t)row * 64;
#pragma unroll
      for (int ks = 0; ks < 8; ks++) {
        const uint* base = (ks < 4) ? r0 : r1;
        a[t][ks] = __builtin_bit_cast(short8, *(const uint4*)(base + (ks & 3) * 16 + q * 4));
      }
    }
    f32x4 acc[2][8];
#pragma unroll
    for (int t = 0; t < 2; t++)
#pragma unroll
      for (int jt = 0; jt < 8; jt++) acc[t][jt] = {0.f, 0.f, 0.f, 0.f};
#pragma unroll
    for (int ks = 0; ks < 8; ks++) {
#pragma unroll
      for (int jt = 0; jt < 8; jt++) {
        short8 b = __builtin_bit_cast(short8, sB[(ks * 8 + jt) * 64 + lane]);
        acc[0][jt] = __builtin_amdgcn_mfma_f32_16x16x32_bf16(a[0][ks], b, acc[0][jt], 0, 0, 0);
        acc[1][jt] = __builtin_amdgcn_mfma_f32_16x16x32_bf16(a[1][ks], b, acc[1][jt], 0, 0, 0);
      }
    }
#pragma unroll
    for (int t = 0; t < 2; t++) {
      float s1[4] = {0.f, 0.f, 0.f, 0.f}, s2[4] = {0.f, 0.f, 0.f, 0.f};
#pragma unroll
      for (int jt = 0; jt < 8; jt++) {
        float bb = blv[jt];
#pragma unroll
        for (int r = 0; r < 4; r++) {
          float v = acc[t][jt][r] + bb;
          s1[r] += v;
          s2[r] += v * v;
        }
      }
#pragma unroll
      for (int off = 1; off < 16; off <<= 1) {
#pragma unroll
        for (int r = 0; r < 4; r++) {
          s1[r] += __shfl_xor(s1[r], off);
          s2[r] += __shfl_xor(s2[r], off);
        }
      }
      float mu[4], rstd[4];
#pragma unroll
      for (int r = 0; r < 4; r++) {
        mu[r] = s1[r] * (1.0f / 128.0f);
        float var = s2[r] * (1.0f / 128.0f) - mu[r] * mu[r];
        rstd[r] = rsqrtf(var + 1e-5f);
      }
      int nodeb = b0 + t * 16 + q * 4;
#pragma unroll
      for (int jt = 0; jt < 8; jt++) {
        float bb = blv[jt];
#pragma unroll
        for (int r = 0; r < 4; r++) {
          int node = nodeb + r;
          if (node < N) {
            float v = acc[t][jt][r] + bb;
            float o = fmaxf((v - mu[r]) * rstd[r] * gv[jt] + bev[jt], 0.0f);
            hout[(size_t)node * 128 + jt * 16 + m] = f2bf(o);
          }
        }
      }
    }
  }
}

// ---- MLP head: out = sigmoid(relu(h1@W1.T+b1) @ W2.T + b2) ----------------

__global__ __launch_bounds__(256) void k_mlp(const uint* __restrict__ h1,
                                             const float* __restrict__ W1,
                                             const float* __restrict__ b1,
                                             const float* __restrict__ W2,
                                             const float* __restrict__ b2,
                                             float* __restrict__ out, int N) {
  __shared__ uint4 sB[1024];  // 16 KB: [ks 0..3][jt 0..3][lane]
  for (int e = threadIdx.x; e < 1024; e += 256) {
    int lane = e & 63, jt = (e >> 6) & 3, ks = e >> 8;
    int m = lane & 15, q = lane >> 4;
    int j = jt * 16 + m;          // 0..63
    int k0 = ks * 32 + q * 8;     // 0..120
    const float* srcr = W1 + (size_t)j * 128 + k0;
    float4 w0 = ((const float4*)srcr)[0];
    float4 w1 = ((const float4*)srcr)[1];
    uint4 p;
    p.x = pack2(w0.x, w0.y);
    p.y = pack2(w0.z, w0.w);
    p.z = pack2(w1.x, w1.y);
    p.w = pack2(w1.z, w1.w);
    sB[e] = p;
  }
  __syncthreads();

  int lane = threadIdx.x & 63, m = lane & 15, q = lane >> 4;
  int w = (blockIdx.x * 256 + threadIdx.x) >> 6;
  int nw = (gridDim.x * 256) >> 6;
  int tiles = (N + 15) / 16;
  float b1v[4], w2v[4];
#pragma unroll
  for (int jt = 0; jt < 4; jt++) {
    b1v[jt] = b1[jt * 16 + m];
    w2v[jt] = W2[jt * 16 + m];
  }
  float b2v = b2[0];
  for (int tl = w; tl < tiles; tl += nw) {
    int b0 = tl * 16;
    int row = b0 + m;
    const uint* r0 = h1 + (size_t)row * 64;
    short8 a[4];
#pragma unroll
    for (int ks = 0; ks < 4; ks++)
      a[ks] = __builtin_bit_cast(short8, *(const uint4*)(r0 + ks * 16 + q * 4));
    f32x4 acc[4];
#pragma unroll
    for (int jt = 0; jt < 4; jt++) acc[jt] = {0.f, 0.f, 0.f, 0.f};
#pragma unroll
    for (int ks = 0; ks < 4; ks++) {
#pragma unroll
      for (int jt = 0; jt < 4; jt++) {
        short8 b = __builtin_bit_cast(short8, sB[(ks * 4 + jt) * 64 + lane]);
        acc[jt] = __builtin_amdgcn_mfma_f32_16x16x32_bf16(a[ks], b, acc[jt], 0, 0, 0);
      }
    }
    float part[4] = {0.f, 0.f, 0.f, 0.f};
#pragma unroll
    for (int jt = 0; jt < 4; jt++) {
#pragma unroll
      for (int r = 0; r < 4; r++)
        part[r] += fmaxf(acc[jt][r] + b1v[jt], 0.0f) * w2v[jt];
    }
#pragma unroll
    for (int off = 1; off < 16; off <<= 1) {
#pragma unroll
      for (int r = 0; r < 4; r++) part[r] += __shfl_xor(part[r], off);
    }
    if (m == 0) {
#pragma unroll
      for (int r = 0; r < 4; r++) {
        int node = b0 + q * 4 + r;
        if (node < N) out[node] = 1.0f / (1.0f + expf(-(part[r] + b2v)));
      }
    }
  }
}

// ---------------------------------------------------------------------------

extern "C" void kernel_launch(void* const* d_in, const int* in_sizes, int n_in,
                              void* d_out, int out_size, void* d_ws, size_t ws_size,
                              hipStream_t stream) {
  const float* x = (const float*)d_in[0];
  const int* ei = (const int*)d_in[1];
  const float* Wl0 = (const float*)d_in[2];
  const float* bl0 = (const float*)d_in[3];
  const float* Wr0 = (const float*)d_in[4];
  const float* g0 = (const float*)d_in[5];
  const float* be0 = (const float*)d_in[6];
  const float* Wl1 = (const float*)d_in[7];
  const float* bl1 = (const float*)d_in[8];
  const float* Wr1 = (const float*)d_in[9];
  const float* g1 = (const float*)d_in[10];
  const float* be1 = (const float*)d_in[11];
  const float* W1 = (const float*)d_in[12];
  const float* b1 = (const float*)d_in[13];
  const float* W2 = (const float*)d_in[14];
  const float* b2 = (const float*)d_in[15];
  float* out = (float*)d_out;

  const int N = in_sizes[0] / 64;
  const int E = in_sizes[1] / 2;
  const int* src = ei;
  const int* dst = ei + E;
  const int nb = ceil_div(N, 1 << NBSHIFT);

  // Workspace (~58.8 MB peak):
  //   misc + csr (6.4 MB) + regionX (25.6 MB) + h0buf (25.6 MB)
  // h0buf timeline: bed (12.8 MB, pass A/B) -> h0 (k_lin0 onward).
  // regionX timeline: [xb | agg0b] -> agg1 -> h1 (in-place).
  char* ws = (char*)d_ws;
  size_t off = 0;
  auto alloc = [&](size_t bytes) -> void* {
    void* p = ws + off;
    off = (off + bytes + 255) & ~(size_t)255;
    return p;
  };
  int* counts = (int*)alloc((size_t)N * 4);
  int* rowst = (int*)alloc((size_t)N * 4);
  int* gbtot = (int*)alloc(512 * 4);
  int* gbase = (int*)alloc(512 * 4);
  int* gbcur = (int*)alloc(512 * 4);
  int* csr = (int*)alloc((size_t)E * 4);
  uint* regionX = (uint*)alloc((size_t)N * 64 * 4);  // 25.6 MB
  uint* h0buf = (uint*)alloc((size_t)N * 64 * 4);    // 25.6 MB

  uint* xb = regionX;                      // N x 32 uints
  uint* agg0b = regionX + (size_t)N * 32;  // N x 32 uints
  uint* agg1 = regionX;                    // N x 64 uints (over dead xb/agg0b)
  int2* bed = (int2*)h0buf;                // E x 8 B, dead before k_lin0

  hipMemsetAsync(gbtot, 0, 512 * 4, stream);

  k_prep<<<ceil_div(N * 32, 256), 256, 0, stream>>>(x, xb, N * 32);
  k_bhist<<<ceil_div(E, ACHUNK), 256, 0, stream>>>(dst, gbtot, E);
  k_bscan<<<1, 512, 0, stream>>>(gbtot, gbase, gbcur);
  k_passA<<<ceil_div(E, ACHUNK), 256, 0, stream>>>(src, dst, gbcur, bed, E);
  k_passB<<<nb, 256, 0, stream>>>(bed, gbase, counts, rowst, csr, N, E);

  k_agg0b<<<2048, 256, 0, stream>>>((const unsigned short*)xb, rowst, counts, csr,
                                    (unsigned short*)agg0b, N);
  k_lin0<<<512, 256, 0, stream>>>(agg0b, xb, Wl0, bl0, Wr0, g0, be0,
                                  (unsigned short*)h0buf, N);
  k_agg1<<<2048, 256, 0, stream>>>(h0buf, rowst, counts, csr, agg1, N);
  k_lin1<<<512, 256, 0, stream>>>(agg1, h0buf, Wl1, bl1, Wr1, g1, be1, N);
  k_mlp<<<512, 256, 0, stream>>>(agg1, W1, b1, W2, b2, out, N);
}

// Round 6
// 347.316 us; speedup vs baseline: 3.6201x; 1.0194x over previous
//
#include <hip/hip_runtime.h>
#include <math.h>

// ---------------------------------------------------------------------------
// GraphSAGE (max aggr) x2 + LN + ReLU + MLP head + sigmoid.
// CSR build via 2-level LDS-staged counting sort (no N-wide global atomics).
// Gather-max aggregation done entirely in the u16 domain:
//   - layer 1: h0 is post-ReLU (>=0) so packed bf16 max == v_pk_max_u16,
//     neutral 0 == "empty neighborhood -> 0" (no unpack, no branch).
//   - layer 0: x is signed -> k_prep stores a monotone u16 remap xm
//     (v<0 ? ~v : v|0x8000); aggregation = v_pk_max_u16; inverse map once
//     per output element. 2 nodes/wave, 4 B/lane loads.
// MFMA GEMM linear layers with fused LN/ReLU/sigmoid epilogues.
// Workspace ~58.8 MB: h0buf = [bed 12.8 | xm 12.8] during CSR/agg0 phase,
// then h0 (25.6) from k_lin0 on; h1 overwrites agg1 in-place.
// ---------------------------------------------------------------------------

static inline int ceil_div(int a, int b) { return (a + b - 1) / b; }

typedef unsigned int uint;
typedef __attribute__((ext_vector_type(8))) short short8;
typedef __attribute__((ext_vector_type(4))) float f32x4;

#define NBSHIFT 8     // bucket = 256 dst nodes
#define ACHUNK 4096   // edges per pass-A block
#define BCAP 6144     // LDS csr-window capacity per bucket (mean ~4096, sd ~64)

// RTNE float -> bf16
__device__ __forceinline__ unsigned short f2bf(float f) {
  uint u = __float_as_uint(f);
  u += 0x7fffu + ((u >> 16) & 1u);
  return (unsigned short)(u >> 16);
}
__device__ __forceinline__ float bfval(unsigned short b) {
  return __uint_as_float((uint)b << 16);
}
__device__ __forceinline__ uint pack2(float lo, float hi) {
  return (uint)f2bf(lo) | ((uint)f2bf(hi) << 16);
}
// packed unsigned 16-bit max (bf16>=0 compares correctly as u16)
__device__ __forceinline__ uint pkmaxu16(uint a, uint b) {
  uint r;
  asm("v_pk_max_u16 %0, %1, %2" : "=v"(r) : "v"(a), "v"(b));
  return r;
}

// ---- bucket histogram (LDS-aggregated) ------------------------------------

__global__ __launch_bounds__(256) void k_bhist(const int* __restrict__ dst,
                                               int* __restrict__ gbtot, int E) {
  __shared__ int bcnt[512];
  int tid = threadIdx.x;
  for (int i = tid; i < 512; i += 256) bcnt[i] = 0;
  __syncthreads();
  int c0 = blockIdx.x * ACHUNK;
  int cend = min(c0 + ACHUNK, E);
  for (int e = c0 + tid; e < cend; e += 256)
    atomicAdd(&bcnt[dst[e] >> NBSHIFT], 1);
  __syncthreads();
  for (int i = tid; i < 512; i += 256) {
    int c = bcnt[i];
    if (c) atomicAdd(&gbtot[i], c);
  }
}

// ---- bucket scan: gbase = exclusive scan of gbtot; gbcur = copy -----------

__global__ __launch_bounds__(512) void k_bscan(const int* __restrict__ gbtot,
                                               int* __restrict__ gbase,
                                               int* __restrict__ gbcur) {
  __shared__ int tmp[512];
  int v = gbtot[threadIdx.x];
  tmp[threadIdx.x] = v;
  __syncthreads();
  for (int off = 1; off < 512; off <<= 1) {
    int t = (threadIdx.x >= off) ? tmp[threadIdx.x - off] : 0;
    __syncthreads();
    tmp[threadIdx.x] += t;
    __syncthreads();
  }
  int ex = tmp[threadIdx.x] - v;
  gbase[threadIdx.x] = ex;
  gbcur[threadIdx.x] = ex;
}

// ---- Pass A: counting-sort edges into bucket-grouped bed[] ----------------

__global__ __launch_bounds__(256) void k_passA(const int* __restrict__ src,
                                               const int* __restrict__ dst,
                                               int* __restrict__ gbcur,
                                               int2* __restrict__ bed, int E) {
  __shared__ int bcnt[512];
  __shared__ int lbase[512];
  __shared__ int bbase[512];
  __shared__ int lcur[512];
  __shared__ int2 sbed[ACHUNK];
  int tid = threadIdx.x;
  int c0 = blockIdx.x * ACHUNK;
  int cend = min(c0 + ACHUNK, E);
  int total = cend - c0;
  for (int i = tid; i < 512; i += 256) bcnt[i] = 0;
  __syncthreads();
  for (int e = c0 + tid; e < cend; e += 256)
    atomicAdd(&bcnt[dst[e] >> NBSHIFT], 1);
  __syncthreads();
  for (int i = tid; i < 512; i += 256) lbase[i] = bcnt[i];
  __syncthreads();
  for (int off = 1; off < 512; off <<= 1) {
    int i0 = tid, i1 = tid + 256;
    int v0 = (i0 >= off) ? lbase[i0 - off] : 0;
    int v1 = (i1 >= off) ? lbase[i1 - off] : 0;
    __syncthreads();
    lbase[i0] += v0;
    lbase[i1] += v1;
    __syncthreads();
  }
  for (int i = tid; i < 512; i += 256) {
    int c = bcnt[i];
    bbase[i] = (c > 0) ? atomicAdd(&gbcur[i], c) : 0;
    lcur[i] = 0;
  }
  __syncthreads();
  for (int e = c0 + tid; e < cend; e += 256) {
    int s = src[e], d = dst[e];
    int b = d >> NBSHIFT;
    int lp = atomicAdd(&lcur[b], 1);
    sbed[lbase[b] - bcnt[b] + lp] = make_int2(s, d);
  }
  __syncthreads();
  for (int j = tid; j < total; j += 256) {
    int2 pr = sbed[j];
    int b = pr.y >> NBSHIFT;
    bed[bbase[b] + (j - (lbase[b] - bcnt[b]))] = pr;
  }
}

// ---- Pass B: one block per bucket; degrees/row-starts in LDS --------------

__global__ __launch_bounds__(256) void k_passB(const int2* __restrict__ bed,
                                               const int* __restrict__ gbase,
                                               int* __restrict__ counts,
                                               int* __restrict__ rowst,
                                               int* __restrict__ csr, int N, int E) {
  __shared__ int cnt[256];
  __shared__ int scn[256];
  __shared__ int lcur[256];
  __shared__ int scsr[BCAP];
  int b = blockIdx.x, tid = threadIdx.x;
  int n0 = b << NBSHIFT;
  int n1 = min(n0 + 256, N);
  int e0 = gbase[b];
  int e1 = (b + 1 < 512) ? gbase[b + 1] : E;
  if (b + 1 == gridDim.x) e1 = E;
  int sz = e1 - e0;
  cnt[tid] = 0;
  __syncthreads();
  for (int e = e0 + tid; e < e1; e += 256)
    atomicAdd(&cnt[bed[e].y - n0], 1);
  __syncthreads();
  scn[tid] = cnt[tid];
  __syncthreads();
  for (int off = 1; off < 256; off <<= 1) {
    int t = (tid >= off) ? scn[tid - off] : 0;
    __syncthreads();
    scn[tid] += t;
    __syncthreads();
  }
  int ex = scn[tid] - cnt[tid];
  if (n0 + tid < n1) {
    counts[n0 + tid] = cnt[tid];
    rowst[n0 + tid] = e0 + ex;
  }
  lcur[tid] = ex;
  __syncthreads();
  if (sz <= BCAP) {
    for (int e = e0 + tid; e < e1; e += 256) {
      int2 pr = bed[e];
      int p = atomicAdd(&lcur[pr.y - n0], 1);
      scsr[p] = pr.x;
    }
    __syncthreads();
    for (int j = tid; j < sz; j += 256) csr[e0 + j] = scsr[j];
  } else {  // statistical overflow fallback (correct, slower)
    for (int e = e0 + tid; e < e1; e += 256) {
      int2 pr = bed[e];
      int p = atomicAdd(&lcur[pr.y - n0], 1);
      csr[e0 + p] = pr.x;
    }
  }
}

// ---- Prep: x fp32 [N][64] -> xb (packed bf16) + xm (monotone u16) ---------

__global__ __launch_bounds__(256) void k_prep(const float* __restrict__ x,
                                              uint* __restrict__ xb,
                                              uint* __restrict__ xm, int total) {
  int i = blockIdx.x * 256 + threadIdx.x;
  if (i < total) {
    float2 v = ((const float2*)x)[i];
    uint p = pack2(v.x, v.y);
    xb[i] = p;
    uint lo = p & 0xFFFFu, hi = p >> 16;
    lo = (lo & 0x8000u) ? (~lo & 0xFFFFu) : (lo | 0x8000u);
    hi = (hi & 0x8000u) ? (~hi & 0xFFFFu) : (hi | 0x8000u);
    xm[i] = lo | (hi << 16);
  }
}

// ---- Aggregation layer 0: monotone-u16 pk_max, 2 nodes/wave ---------------
// Each half-wave (32 lanes) owns one node; lane covers 2 features (uint).
// Index broadcast within half via __shfl with computed lane (ds_bpermute).

__global__ __launch_bounds__(256) void k_agg0b(const uint* __restrict__ xm,
                                               const int* __restrict__ rowst,
                                               const int* __restrict__ deg,
                                               const int* __restrict__ csr,
                                               uint* __restrict__ agg, int N) {
  int lane = threadIdx.x & 63;
  int sub = lane >> 5, ll = lane & 31;
  int h = sub << 5;
  int w = (blockIdx.x * 256 + threadIdx.x) >> 6;
  int nw = (gridDim.x * 256) >> 6;
  for (int n0 = w * 2; n0 < N; n0 += nw * 2) {
    int n = n0 + sub;
    bool valid = (n < N);
    int myn = valid ? n : (N - 1);
    int rs = rowst[myn], d = deg[myn];
    int dmax = max(d, __shfl_xor(d, 32));
    int dmin = min(d, __shfl_xor(d, 32));
    uint m = 0;
    for (int base = 0; base < dmax; base += 32) {
      int cnt = min(max(d - base, 0), 32);
      int cmin = min(max(dmin - base, 0), 32);
      int cmax = min(dmax - base, 32);
      int idx = (ll < cnt) ? csr[rs + base + ll] : 0;
      int j = 0;
      for (; j + 4 <= cmin; j += 4) {
        int s0 = __shfl(idx, h + j + 0);
        int s1 = __shfl(idx, h + j + 1);
        int s2 = __shfl(idx, h + j + 2);
        int s3 = __shfl(idx, h + j + 3);
        uint u0 = xm[(size_t)s0 * 32 + ll];
        uint u1 = xm[(size_t)s1 * 32 + ll];
        uint u2 = xm[(size_t)s2 * 32 + ll];
        uint u3 = xm[(size_t)s3 * 32 + ll];
        m = pkmaxu16(m, pkmaxu16(pkmaxu16(u0, u1), pkmaxu16(u2, u3)));
      }
      for (; j < cmax; j++) {
        int s = __shfl(idx, h + j);
        uint u = 0;
        if (j < cnt) u = xm[(size_t)s * 32 + ll];
        m = pkmaxu16(m, u);
      }
    }
    if (valid) {
      uint lo = m & 0xFFFFu, hi = m >> 16;
      lo = (lo & 0x8000u) ? (lo ^ 0x8000u) : (~lo & 0xFFFFu);
      hi = (hi & 0x8000u) ? (hi ^ 0x8000u) : (~hi & 0xFFFFu);
      agg[(size_t)n * 32 + ll] = (d > 0) ? (lo | (hi << 16)) : 0u;
    }
  }
}

// ---- Aggregation layer 1: h0 >= 0 -> plain v_pk_max_u16, neutral 0 --------

__global__ __launch_bounds__(256) void k_agg1(const uint* __restrict__ h0,
                                              const int* __restrict__ rowst,
                                              const int* __restrict__ deg,
                                              const int* __restrict__ csr,
                                              uint* __restrict__ agg, int N) {
  int lane = threadIdx.x & 63;
  int wid = (blockIdx.x * 256 + threadIdx.x) >> 6;
  int nw = (gridDim.x * 256) >> 6;
  for (int n = wid; n < N; n += nw) {
    int rs = rowst[n], d = deg[n];
    uint m = 0;
    for (int base = 0; base < d; base += 64) {
      int cnt = min(d - base, 64);
      int idx = (lane < cnt) ? csr[rs + base + lane] : 0;
      int j = 0;
      for (; j + 8 <= cnt; j += 8) {
        uint u0 = h0[(size_t)__shfl(idx, j + 0) * 64 + lane];
        uint u1 = h0[(size_t)__shfl(idx, j + 1) * 64 + lane];
        uint u2 = h0[(size_t)__shfl(idx, j + 2) * 64 + lane];
        uint u3 = h0[(size_t)__shfl(idx, j + 3) * 64 + lane];
        uint u4 = h0[(size_t)__shfl(idx, j + 4) * 64 + lane];
        uint u5 = h0[(size_t)__shfl(idx, j + 5) * 64 + lane];
        uint u6 = h0[(size_t)__shfl(idx, j + 6) * 64 + lane];
        uint u7 = h0[(size_t)__shfl(idx, j + 7) * 64 + lane];
        m = pkmaxu16(m, pkmaxu16(pkmaxu16(pkmaxu16(u0, u1), pkmaxu16(u2, u3)),
                                 pkmaxu16(pkmaxu16(u4, u5), pkmaxu16(u6, u7))));
      }
      for (; j < cnt; j++)
        m = pkmaxu16(m, h0[(size_t)__shfl(idx, j) * 64 + lane]);
    }
    agg[(size_t)n * 64 + lane] = m;  // m==0 for empty == required semantics
  }
}

// ---- Layer 0: h0 = LNrelu([agg0|x] @ [Wl0|Wr0]^T + bl0) -------------------

__global__ __launch_bounds__(256) void k_lin0(
    const uint* __restrict__ agg,  // N x 32 uints (bf16 [N][64])
    const uint* __restrict__ xb,   // N x 32 uints
    const float* __restrict__ Wl, const float* __restrict__ bl,
    const float* __restrict__ Wr, const float* __restrict__ g,
    const float* __restrict__ be, unsigned short* __restrict__ hout, int N) {
  __shared__ uint4 sB[4096];  // 64 KB: [ks 0..7][jt 0..7][lane 0..63]
  for (int e = threadIdx.x; e < 4096; e += 256) {
    int lane = e & 63, jt = (e >> 6) & 7, ks = e >> 9;
    int m = lane & 15, q = lane >> 4;
    int j = jt * 16 + m;
    int half = ks >> 2;             // 0 = hi, 1 = lo
    int kk = (ks & 3) * 32 + q * 8; // 0..120
    const float* srcr = (kk < 64) ? (Wl + (size_t)j * 64 + kk)
                                  : (Wr + (size_t)j * 64 + (kk - 64));
    float4 w0 = ((const float4*)srcr)[0];
    float4 w1 = ((const float4*)srcr)[1];
    float v[8] = {w0.x, w0.y, w0.z, w0.w, w1.x, w1.y, w1.z, w1.w};
    unsigned short b16[8];
#pragma unroll
    for (int i = 0; i < 8; i++) {
      unsigned short hi = f2bf(v[i]);
      b16[i] = half ? f2bf(v[i] - bfval(hi)) : hi;
    }
    uint4 p;
    p.x = (uint)b16[0] | ((uint)b16[1] << 16);
    p.y = (uint)b16[2] | ((uint)b16[3] << 16);
    p.z = (uint)b16[4] | ((uint)b16[5] << 16);
    p.w = (uint)b16[6] | ((uint)b16[7] << 16);
    sB[e] = p;
  }
  __syncthreads();

  int lane = threadIdx.x & 63, m = lane & 15, q = lane >> 4;
  int w = (blockIdx.x * 256 + threadIdx.x) >> 6;
  int nw = (gridDim.x * 256) >> 6;
  int pairs = (N + 31) / 32;
  float blv[8], gv[8], bev[8];
#pragma unroll
  for (int jt = 0; jt < 8; jt++) {
    blv[jt] = bl[jt * 16 + m];
    gv[jt] = g[jt * 16 + m];
    bev[jt] = be[jt * 16 + m];
  }
  for (int p = w; p < pairs; p += nw) {
    int b0 = p * 32;
    short8 a[2][4];
#pragma unroll
    for (int t = 0; t < 2; t++) {
      int row = b0 + t * 16 + m;
      const uint* r0 = agg + (size_t)row * 32;
      const uint* r1 = xb + (size_t)row * 32;
#pragma unroll
      for (int ks = 0; ks < 4; ks++) {
        const uint* base = (ks < 2) ? r0 : r1;
        a[t][ks] = __builtin_bit_cast(short8, *(const uint4*)(base + (ks & 1) * 16 + q * 4));
      }
    }
    f32x4 acc[2][8];
#pragma unroll
    for (int t = 0; t < 2; t++)
#pragma unroll
      for (int jt = 0; jt < 8; jt++) acc[t][jt] = {0.f, 0.f, 0.f, 0.f};
#pragma unroll
    for (int ks = 0; ks < 8; ks++) {
#pragma unroll
      for (int jt = 0; jt < 8; jt++) {
        short8 b = __builtin_bit_cast(short8, sB[(ks * 8 + jt) * 64 + lane]);
        acc[0][jt] = __builtin_amdgcn_mfma_f32_16x16x32_bf16(a[0][ks & 3], b, acc[0][jt], 0, 0, 0);
        acc[1][jt] = __builtin_amdgcn_mfma_f32_16x16x32_bf16(a[1][ks & 3], b, acc[1][jt], 0, 0, 0);
      }
    }
#pragma unroll
    for (int t = 0; t < 2; t++) {
      float s1[4] = {0.f, 0.f, 0.f, 0.f}, s2[4] = {0.f, 0.f, 0.f, 0.f};
#pragma unroll
      for (int jt = 0; jt < 8; jt++) {
        float bb = blv[jt];
#pragma unroll
        for (int r = 0; r < 4; r++) {
          float v = acc[t][jt][r] + bb;
          s1[r] += v;
          s2[r] += v * v;
        }
      }
#pragma unroll
      for (int off = 1; off < 16; off <<= 1) {
#pragma unroll
        for (int r = 0; r < 4; r++) {
          s1[r] += __shfl_xor(s1[r], off);
          s2[r] += __shfl_xor(s2[r], off);
        }
      }
      float mu[4], rstd[4];
#pragma unroll
      for (int r = 0; r < 4; r++) {
        mu[r] = s1[r] * (1.0f / 128.0f);
        float var = s2[r] * (1.0f / 128.0f) - mu[r] * mu[r];
        rstd[r] = rsqrtf(var + 1e-5f);
      }
      int nodeb = b0 + t * 16 + q * 4;
#pragma unroll
      for (int jt = 0; jt < 8; jt++) {
        float bb = blv[jt];
#pragma unroll
        for (int r = 0; r < 4; r++) {
          int node = nodeb + r;
          if (node < N) {
            float v = acc[t][jt][r] + bb;
            float o = fmaxf((v - mu[r]) * rstd[r] * gv[jt] + bev[jt], 0.0f);
            hout[(size_t)node * 128 + jt * 16 + m] = f2bf(o);
          }
        }
      }
    }
  }
}

// ---- Layer 1: h1 = LNrelu([agg1|h0] @ [Wl1|Wr1]^T + bl1), in-place --------

__global__ __launch_bounds__(256) void k_lin1(
    uint* agg,                     // N x 64 uints; becomes h1 (bf16 [N][128])
    const uint* __restrict__ h0,   // N x 64 uints
    const float* __restrict__ Wl, const float* __restrict__ bl,
    const float* __restrict__ Wr, const float* __restrict__ g,
    const float* __restrict__ be, int N) {
  __shared__ uint4 sB[4096];  // 64 KB
  for (int e = threadIdx.x; e < 4096; e += 256) {
    int lane = e & 63, jt = (e >> 6) & 7, ks = e >> 9;
    int m = lane & 15, q = lane >> 4;
    int j = jt * 16 + m;
    int k0 = ks * 32 + q * 8;  // 0..248
    const float* srcr = (k0 < 128) ? (Wl + (size_t)j * 128 + k0)
                                   : (Wr + (size_t)j * 128 + (k0 - 128));
    float4 w0 = ((const float4*)srcr)[0];
    float4 w1 = ((const float4*)srcr)[1];
    uint4 p;
    p.x = pack2(w0.x, w0.y);
    p.y = pack2(w0.z, w0.w);
    p.z = pack2(w1.x, w1.y);
    p.w = pack2(w1.z, w1.w);
    sB[e] = p;
  }
  __syncthreads();

  int lane = threadIdx.x & 63, m = lane & 15, q = lane >> 4;
  int w = (blockIdx.x * 256 + threadIdx.x) >> 6;
  int nw = (gridDim.x * 256) >> 6;
  int pairs = (N + 31) / 32;
  float blv[8], gv[8], bev[8];
#pragma unroll
  for (int jt = 0; jt < 8; jt++) {
    blv[jt] = bl[jt * 16 + m];
    gv[jt] = g[jt * 16 + m];
    bev[jt] = be[jt * 16 + m];
  }
  unsigned short* hout = (unsigned short*)agg;
  for (int p = w; p < pairs; p += nw) {
    int b0 = p * 32;
    short8 a[2][8];
#pragma unroll
    for (int t = 0; t < 2; t++) {
      int row = b0 + t * 16 + m;
      const uint* r0 = agg + (size_t)row * 64;
      const uint* r1 = h0 + (size_t)row * 64;
#pragma unroll
      for (int ks = 0; ks < 8; ks++) {
        const uint* base = (ks < 4) ? r0 : r1;
        a[t][ks] = __builtin_bit_cast(short8, *(const uint4*)(base + (ks & 3) * 16 + q * 4));
      }
    }
    f32x4 acc[2][8];
#pragma unroll
    for (int t = 0; t < 2; t++)
#pragma unroll
      for (int jt = 0; jt < 8; jt++) acc[t][jt] = {0.f, 0.f, 0.f, 0.f};
#pragma unroll
    for (int ks = 0; ks < 8; ks++) {
#pragma unroll
      for (int jt = 0; jt < 8; jt++) {
        short8 b = __builtin_bit_cast(short8, sB[(ks * 8 + jt) * 64 + lane]);
        acc[0][jt] = __builtin_amdgcn_mfma_f32_16x16x32_bf16(a[0][ks], b, acc[0][jt], 0, 0, 0);
        acc[1][jt] = __builtin_amdgcn_mfma_f32_16x16x32_bf16(a[1][ks], b, acc[1][jt], 0, 0, 0);
      }
    }
#pragma unroll
    for (int t = 0; t < 2; t++) {
      float s1[4] = {0.f, 0.f, 0.f, 0.f}, s2[4] = {0.f, 0.f, 0.f, 0.f};
#pragma unroll
      for (int jt = 0; jt < 8; jt++) {
        float bb = blv[jt];
#pragma unroll
        for (int r = 0; r < 4; r++) {
          float v = acc[t][jt][r] + bb;
          s1[r] += v;
          s2[r] += v * v;
        }
      }
#pragma unroll
      for (int off = 1; off < 16; off <<= 1) {
#pragma unroll
        for (int r = 0; r < 4; r++) {
          s1[r] += __shfl_xor(s1[r], off);
          s2[r] += __shfl_xor(s2[r], off);
        }
      }
      float mu[4], rstd[4];
#pragma unroll
      for (int r = 0; r < 4; r++) {
        mu[r] = s1[r] * (1.0f / 128.0f);
        float var = s2[r] * (1.0f / 128.0f) - mu[r] * mu[r];
        rstd[r] = rsqrtf(var + 1e-5f);
      }
      int nodeb = b0 + t * 16 + q * 4;
#pragma unroll
      for (int jt = 0; jt < 8; jt++) {
        float bb = blv[jt];
#pragma unroll
        for (int r = 0; r < 4; r++) {
          int node = nodeb + r;
          if (node < N) {
            float v = acc[t][jt][r] + bb;
            float o = fmaxf((v - mu[r]) * rstd[r] * gv[jt] + bev[jt], 0.0f);
            hout[(size_t)node * 128 + jt * 16 + m] = f2bf(o);
          }
        }
      }
    }
  }
}

// ---- MLP head: out = sigmoid(relu(h1@W1.T+b1) @ W2.T + b2) ----------------

__global__ __launch_bounds__(256) void k_mlp(const uint* __restrict__ h1,
                                             const float* __restrict__ W1,
                                             const float* __restrict__ b1,
                                             const float* __restrict__ W2,
                                             const float* __restrict__ b2,
                                             float* __restrict__ out, int N) {
  __shared__ uint4 sB[1024];  // 16 KB: [ks 0..3][jt 0..3][lane]
  for (int e = threadIdx.x; e < 1024; e += 256) {
    int lane = e & 63, jt = (e >> 6) & 3, ks = e >> 8;
    int m = lane & 15, q = lane >> 4;
    int j = jt * 16 + m;          // 0..63
    int k0 = ks * 32 + q * 8;     // 0..120
    const float* srcr = W1 + (size_t)j * 128 + k0;
    float4 w0 = ((const float4*)srcr)[0];
    float4 w1 = ((const float4*)srcr)[1];
    uint4 p;
    p.x = pack2(w0.x, w0.y);
    p.y = pack2(w0.z, w0.w);
    p.z = pack2(w1.x, w1.y);
    p.w = pack2(w1.z, w1.w);
    sB[e] = p;
  }
  __syncthreads();

  int lane = threadIdx.x & 63, m = lane & 15, q = lane >> 4;
  int w = (blockIdx.x * 256 + threadIdx.x) >> 6;
  int nw = (gridDim.x * 256) >> 6;
  int tiles = (N + 15) / 16;
  float b1v[4], w2v[4];
#pragma unroll
  for (int jt = 0; jt < 4; jt++) {
    b1v[jt] = b1[jt * 16 + m];
    w2v[jt] = W2[jt * 16 + m];
  }
  float b2v = b2[0];
  for (int tl = w; tl < tiles; tl += nw) {
    int b0 = tl * 16;
    int row = b0 + m;
    const uint* r0 = h1 + (size_t)row * 64;
    short8 a[4];
#pragma unroll
    for (int ks = 0; ks < 4; ks++)
      a[ks] = __builtin_bit_cast(short8, *(const uint4*)(r0 + ks * 16 + q * 4));
    f32x4 acc[4];
#pragma unroll
    for (int jt = 0; jt < 4; jt++) acc[jt] = {0.f, 0.f, 0.f, 0.f};
#pragma unroll
    for (int ks = 0; ks < 4; ks++) {
#pragma unroll
      for (int jt = 0; jt < 4; jt++) {
        short8 b = __builtin_bit_cast(short8, sB[(ks * 4 + jt) * 64 + lane]);
        acc[jt] = __builtin_amdgcn_mfma_f32_16x16x32_bf16(a[ks], b, acc[jt], 0, 0, 0);
      }
    }
    float part[4] = {0.f, 0.f, 0.f, 0.f};
#pragma unroll
    for (int jt = 0; jt < 4; jt++) {
#pragma unroll
      for (int r = 0; r < 4; r++)
        part[r] += fmaxf(acc[jt][r] + b1v[jt], 0.0f) * w2v[jt];
    }
#pragma unroll
    for (int off = 1; off < 16; off <<= 1) {
#pragma unroll
      for (int r = 0; r < 4; r++) part[r] += __shfl_xor(part[r], off);
    }
    if (m == 0) {
#pragma unroll
      for (int r = 0; r < 4; r++) {
        int node = b0 + q * 4 + r;
        if (node < N) out[node] = 1.0f / (1.0f + expf(-(part[r] + b2v)));
      }
    }
  }
}

// ---------------------------------------------------------------------------

extern "C" void kernel_launch(void* const* d_in, const int* in_sizes, int n_in,
                              void* d_out, int out_size, void* d_ws, size_t ws_size,
                              hipStream_t stream) {
  const float* x = (const float*)d_in[0];
  const int* ei = (const int*)d_in[1];
  const float* Wl0 = (const float*)d_in[2];
  const float* bl0 = (const float*)d_in[3];
  const float* Wr0 = (const float*)d_in[4];
  const float* g0 = (const float*)d_in[5];
  const float* be0 = (const float*)d_in[6];
  const float* Wl1 = (const float*)d_in[7];
  const float* bl1 = (const float*)d_in[8];
  const float* Wr1 = (const float*)d_in[9];
  const float* g1 = (const float*)d_in[10];
  const float* be1 = (const float*)d_in[11];
  const float* W1 = (const float*)d_in[12];
  const float* b1 = (const float*)d_in[13];
  const float* W2 = (const float*)d_in[14];
  const float* b2 = (const float*)d_in[15];
  float* out = (float*)d_out;

  const int N = in_sizes[0] / 64;
  const int E = in_sizes[1] / 2;
  const int* src = ei;
  const int* dst = ei + E;
  const int nb = ceil_div(N, 1 << NBSHIFT);

  // Workspace (~58.8 MB peak):
  //   misc + csr (6.4 MB) + regionX (25.6 MB) + h0buf (25.6 MB)
  // h0buf timeline: [bed 12.8 | xm 12.8] -> h0 (k_lin0 onward).
  // regionX timeline: [xb | agg0b] -> agg1 -> h1 (in-place).
  char* ws = (char*)d_ws;
  size_t off = 0;
  auto alloc = [&](size_t bytes) -> void* {
    void* p = ws + off;
    off = (off + bytes + 255) & ~(size_t)255;
    return p;
  };
  int* counts = (int*)alloc((size_t)N * 4);
  int* rowst = (int*)alloc((size_t)N * 4);
  int* gbtot = (int*)alloc(512 * 4);
  int* gbase = (int*)alloc(512 * 4);
  int* gbcur = (int*)alloc(512 * 4);
  int* csr = (int*)alloc((size_t)E * 4);
  uint* regionX = (uint*)alloc((size_t)N * 64 * 4);  // 25.6 MB
  uint* h0buf = (uint*)alloc((size_t)N * 64 * 4);    // 25.6 MB

  uint* xb = regionX;                      // N x 32 uints
  uint* agg0b = regionX + (size_t)N * 32;  // N x 32 uints
  uint* agg1 = regionX;                    // N x 64 uints (over dead xb/agg0b)
  int2* bed = (int2*)h0buf;                // E x 8 B = first N*32 uints
  uint* xm = h0buf + (size_t)N * 32;       // monotone u16 x (12.8 MB)

  hipMemsetAsync(gbtot, 0, 512 * 4, stream);

  k_prep<<<ceil_div(N * 32, 256), 256, 0, stream>>>(x, xb, xm, N * 32);
  k_bhist<<<ceil_div(E, ACHUNK), 256, 0, stream>>>(dst, gbtot, E);
  k_bscan<<<1, 512, 0, stream>>>(gbtot, gbase, gbcur);
  k_passA<<<ceil_div(E, ACHUNK), 256, 0, stream>>>(src, dst, gbcur, bed, E);
  k_passB<<<nb, 256, 0, stream>>>(bed, gbase, counts, rowst, csr, N, E);

  k_agg0b<<<2048, 256, 0, stream>>>(xm, rowst, counts, csr, agg0b, N);
  k_lin0<<<512, 256, 0, stream>>>(agg0b, xb, Wl0, bl0, Wr0, g0, be0,
                                  (unsigned short*)h0buf, N);
  k_agg1<<<2048, 256, 0, stream>>>(h0buf, rowst, counts, csr, agg1, N);
  k_lin1<<<512, 256, 0, stream>>>(agg1, h0buf, Wl1, bl1, Wr1, g1, be1, N);
  k_mlp<<<512, 256, 0, stream>>>(agg1, W1, b1, W2, b2, out, N);
}

// Round 7
// 322.722 us; speedup vs baseline: 3.8960x; 1.0762x over previous
//
#include <hip/hip_runtime.h>
#include <math.h>

// ---------------------------------------------------------------------------
// GraphSAGE (max aggr) x2 + LN + ReLU + MLP head + sigmoid.
// CSR build via 2-level LDS-staged counting sort (no N-wide global atomics).
// Gather-max in the u16 domain (v_pk_max_u16; monotone remap for signed x),
// with DUPLICATE-PADDED 8-deep gather groups (max is idempotent -> lanes past
// cnt point at the first neighbor; zero serial tail loads).
// MFMA GEMM linear layers read pre-packed bf16 B-fragments straight from
// global (k_wprep packs them once; 64/64/16 KB tables stay L2-resident) --
// no LDS staging, no __syncthreads in the GEMM kernels.
// Workspace ~58.9 MB: h0buf = [bed 12.8 | xm 12.8] during CSR/agg0 phase,
// then h0 (25.6) from k_lin0 on; h1 overwrites agg1 in-place.
// ---------------------------------------------------------------------------

static inline int ceil_div(int a, int b) { return (a + b - 1) / b; }

typedef unsigned int uint;
typedef __attribute__((ext_vector_type(8))) short short8;
typedef __attribute__((ext_vector_type(4))) float f32x4;

#define NBSHIFT 8     // bucket = 256 dst nodes
#define ACHUNK 4096   // edges per pass-A block
#define BCAP 6144     // LDS csr-window capacity per bucket (mean ~4096, sd ~64)

// RTNE float -> bf16
__device__ __forceinline__ unsigned short f2bf(float f) {
  uint u = __float_as_uint(f);
  u += 0x7fffu + ((u >> 16) & 1u);
  return (unsigned short)(u >> 16);
}
__device__ __forceinline__ float bfval(unsigned short b) {
  return __uint_as_float((uint)b << 16);
}
__device__ __forceinline__ uint pack2(float lo, float hi) {
  return (uint)f2bf(lo) | ((uint)f2bf(hi) << 16);
}
// packed unsigned 16-bit max (bf16>=0 compares correctly as u16)
__device__ __forceinline__ uint pkmaxu16(uint a, uint b) {
  uint r;
  asm("v_pk_max_u16 %0, %1, %2" : "=v"(r) : "v"(a), "v"(b));
  return r;
}

// ---- bucket histogram (LDS-aggregated) ------------------------------------

__global__ __launch_bounds__(256) void k_bhist(const int* __restrict__ dst,
                                               int* __restrict__ gbtot, int E) {
  __shared__ int bcnt[512];
  int tid = threadIdx.x;
  for (int i = tid; i < 512; i += 256) bcnt[i] = 0;
  __syncthreads();
  int c0 = blockIdx.x * ACHUNK;
  int cend = min(c0 + ACHUNK, E);
  for (int e = c0 + tid; e < cend; e += 256)
    atomicAdd(&bcnt[dst[e] >> NBSHIFT], 1);
  __syncthreads();
  for (int i = tid; i < 512; i += 256) {
    int c = bcnt[i];
    if (c) atomicAdd(&gbtot[i], c);
  }
}

// ---- bucket scan: gbase = exclusive scan of gbtot; gbcur = copy -----------

__global__ __launch_bounds__(512) void k_bscan(const int* __restrict__ gbtot,
                                               int* __restrict__ gbase,
                                               int* __restrict__ gbcur) {
  __shared__ int tmp[512];
  int v = gbtot[threadIdx.x];
  tmp[threadIdx.x] = v;
  __syncthreads();
  for (int off = 1; off < 512; off <<= 1) {
    int t = (threadIdx.x >= off) ? tmp[threadIdx.x - off] : 0;
    __syncthreads();
    tmp[threadIdx.x] += t;
    __syncthreads();
  }
  int ex = tmp[threadIdx.x] - v;
  gbase[threadIdx.x] = ex;
  gbcur[threadIdx.x] = ex;
}

// ---- Pass A: counting-sort edges into bucket-grouped bed[] ----------------

__global__ __launch_bounds__(256) void k_passA(const int* __restrict__ src,
                                               const int* __restrict__ dst,
                                               int* __restrict__ gbcur,
                                               int2* __restrict__ bed, int E) {
  __shared__ int bcnt[512];
  __shared__ int lbase[512];
  __shared__ int bbase[512];
  __shared__ int lcur[512];
  __shared__ int2 sbed[ACHUNK];
  int tid = threadIdx.x;
  int c0 = blockIdx.x * ACHUNK;
  int cend = min(c0 + ACHUNK, E);
  int total = cend - c0;
  for (int i = tid; i < 512; i += 256) bcnt[i] = 0;
  __syncthreads();
  for (int e = c0 + tid; e < cend; e += 256)
    atomicAdd(&bcnt[dst[e] >> NBSHIFT], 1);
  __syncthreads();
  for (int i = tid; i < 512; i += 256) lbase[i] = bcnt[i];
  __syncthreads();
  for (int off = 1; off < 512; off <<= 1) {
    int i0 = tid, i1 = tid + 256;
    int v0 = (i0 >= off) ? lbase[i0 - off] : 0;
    int v1 = (i1 >= off) ? lbase[i1 - off] : 0;
    __syncthreads();
    lbase[i0] += v0;
    lbase[i1] += v1;
    __syncthreads();
  }
  for (int i = tid; i < 512; i += 256) {
    int c = bcnt[i];
    bbase[i] = (c > 0) ? atomicAdd(&gbcur[i], c) : 0;
    lcur[i] = 0;
  }
  __syncthreads();
  for (int e = c0 + tid; e < cend; e += 256) {
    int s = src[e], d = dst[e];
    int b = d >> NBSHIFT;
    int lp = atomicAdd(&lcur[b], 1);
    sbed[lbase[b] - bcnt[b] + lp] = make_int2(s, d);
  }
  __syncthreads();
  for (int j = tid; j < total; j += 256) {
    int2 pr = sbed[j];
    int b = pr.y >> NBSHIFT;
    bed[bbase[b] + (j - (lbase[b] - bcnt[b]))] = pr;
  }
}

// ---- Pass B: one block per bucket; degrees/row-starts in LDS --------------

__global__ __launch_bounds__(256) void k_passB(const int2* __restrict__ bed,
                                               const int* __restrict__ gbase,
                                               int* __restrict__ counts,
                                               int* __restrict__ rowst,
                                               int* __restrict__ csr, int N, int E) {
  __shared__ int cnt[256];
  __shared__ int scn[256];
  __shared__ int lcur[256];
  __shared__ int scsr[BCAP];
  int b = blockIdx.x, tid = threadIdx.x;
  int n0 = b << NBSHIFT;
  int n1 = min(n0 + 256, N);
  int e0 = gbase[b];
  int e1 = (b + 1 < 512) ? gbase[b + 1] : E;
  if (b + 1 == gridDim.x) e1 = E;
  int sz = e1 - e0;
  cnt[tid] = 0;
  __syncthreads();
  for (int e = e0 + tid; e < e1; e += 256)
    atomicAdd(&cnt[bed[e].y - n0], 1);
  __syncthreads();
  scn[tid] = cnt[tid];
  __syncthreads();
  for (int off = 1; off < 256; off <<= 1) {
    int t = (tid >= off) ? scn[tid - off] : 0;
    __syncthreads();
    scn[tid] += t;
    __syncthreads();
  }
  int ex = scn[tid] - cnt[tid];
  if (n0 + tid < n1) {
    counts[n0 + tid] = cnt[tid];
    rowst[n0 + tid] = e0 + ex;
  }
  lcur[tid] = ex;
  __syncthreads();
  if (sz <= BCAP) {
    for (int e = e0 + tid; e < e1; e += 256) {
      int2 pr = bed[e];
      int p = atomicAdd(&lcur[pr.y - n0], 1);
      scsr[p] = pr.x;
    }
    __syncthreads();
    for (int j = tid; j < sz; j += 256) csr[e0 + j] = scsr[j];
  } else {  // statistical overflow fallback (correct, slower)
    for (int e = e0 + tid; e < e1; e += 256) {
      int2 pr = bed[e];
      int p = atomicAdd(&lcur[pr.y - n0], 1);
      csr[e0 + p] = pr.x;
    }
  }
}

// ---- Prep: x fp32 [N][64] -> xb (packed bf16) + xm (monotone u16) ---------

__global__ __launch_bounds__(256) void k_prep(const float* __restrict__ x,
                                              uint* __restrict__ xb,
                                              uint* __restrict__ xm, int total) {
  int i = blockIdx.x * 256 + threadIdx.x;
  if (i < total) {
    float2 v = ((const float2*)x)[i];
    uint p = pack2(v.x, v.y);
    xb[i] = p;
    uint lo = p & 0xFFFFu, hi = p >> 16;
    lo = (lo & 0x8000u) ? (~lo & 0xFFFFu) : (lo | 0x8000u);
    hi = (hi & 0x8000u) ? (~hi & 0xFFFFu) : (hi | 0x8000u);
    xm[i] = lo | (hi << 16);
  }
}

// ---- Weight prep: pack all GEMM B-operands as bf16 fragments --------------
// wB0: layer0, hi/lo split (8 ks-steps) [4096 uint4]
// wB1: layer1 K=256 [4096 uint4];  wBm: MLP W1 [1024 uint4]

__global__ __launch_bounds__(256) void k_wprep(
    const float* __restrict__ Wl0, const float* __restrict__ Wr0,
    const float* __restrict__ Wl1, const float* __restrict__ Wr1,
    const float* __restrict__ W1m,
    uint4* __restrict__ wB0, uint4* __restrict__ wB1, uint4* __restrict__ wBm) {
  int i = blockIdx.x * 256 + threadIdx.x;
  if (i < 4096) {
    int lane = i & 63, jt = (i >> 6) & 7, ks = i >> 9;
    int m = lane & 15, q = lane >> 4;
    int j = jt * 16 + m;
    int half = ks >> 2;             // 0 = hi, 1 = lo
    int kk = (ks & 3) * 32 + q * 8; // 0..120
    const float* srcr = (kk < 64) ? (Wl0 + (size_t)j * 64 + kk)
                                  : (Wr0 + (size_t)j * 64 + (kk - 64));
    float4 w0 = ((const float4*)srcr)[0];
    float4 w1 = ((const float4*)srcr)[1];
    float v[8] = {w0.x, w0.y, w0.z, w0.w, w1.x, w1.y, w1.z, w1.w};
    unsigned short b16[8];
#pragma unroll
    for (int t = 0; t < 8; t++) {
      unsigned short hi = f2bf(v[t]);
      b16[t] = half ? f2bf(v[t] - bfval(hi)) : hi;
    }
    uint4 p;
    p.x = (uint)b16[0] | ((uint)b16[1] << 16);
    p.y = (uint)b16[2] | ((uint)b16[3] << 16);
    p.z = (uint)b16[4] | ((uint)b16[5] << 16);
    p.w = (uint)b16[6] | ((uint)b16[7] << 16);
    wB0[i] = p;
  } else if (i < 8192) {
    int e = i - 4096;
    int lane = e & 63, jt = (e >> 6) & 7, ks = e >> 9;
    int m = lane & 15, q = lane >> 4;
    int j = jt * 16 + m;
    int k0 = ks * 32 + q * 8;  // 0..248
    const float* srcr = (k0 < 128) ? (Wl1 + (size_t)j * 128 + k0)
                                   : (Wr1 + (size_t)j * 128 + (k0 - 128));
    float4 w0 = ((const float4*)srcr)[0];
    float4 w1 = ((const float4*)srcr)[1];
    uint4 p;
    p.x = pack2(w0.x, w0.y);
    p.y = pack2(w0.z, w0.w);
    p.z = pack2(w1.x, w1.y);
    p.w = pack2(w1.z, w1.w);
    wB1[e] = p;
  } else if (i < 9216) {
    int e = i - 8192;
    int lane = e & 63, jt = (e >> 6) & 3, ks = e >> 8;
    int m = lane & 15, q = lane >> 4;
    int j = jt * 16 + m;          // 0..63
    int k0 = ks * 32 + q * 8;     // 0..120
    const float* srcr = W1m + (size_t)j * 128 + k0;
    float4 w0 = ((const float4*)srcr)[0];
    float4 w1 = ((const float4*)srcr)[1];
    uint4 p;
    p.x = pack2(w0.x, w0.y);
    p.y = pack2(w0.z, w0.w);
    p.z = pack2(w1.x, w1.y);
    p.w = pack2(w1.z, w1.w);
    wBm[e] = p;
  }
}

// ---- Aggregation layer 0: monotone-u16 pk_max, 2 nodes/wave ---------------
// Duplicate-padded groups: lanes past cnt hold the first neighbor; max is
// idempotent, so every group is an unconditional 8-deep parallel gather.

__global__ __launch_bounds__(256) void k_agg0b(const uint* __restrict__ xm,
                                               const int* __restrict__ rowst,
                                               const int* __restrict__ deg,
                                               const int* __restrict__ csr,
                                               uint* __restrict__ agg, int N) {
  int lane = threadIdx.x & 63;
  int sub = lane >> 5, ll = lane & 31;
  int h = sub << 5;
  int w = (blockIdx.x * 256 + threadIdx.x) >> 6;
  int nw = (gridDim.x * 256) >> 6;
  for (int n0 = w * 2; n0 < N; n0 += nw * 2) {
    int n = n0 + sub;
    bool valid = (n < N);
    int myn = valid ? n : (N - 1);
    int rs = rowst[myn], d = deg[myn];
    int dmax = max(d, __shfl_xor(d, 32));
    int fb = (d > 0) ? csr[rs] : 0;  // first neighbor (duplicate pad)
    uint m = 0;
    for (int base = 0; base < dmax; base += 32) {
      int cnt = min(max(d - base, 0), 32);
      int cmax = min(dmax - base, 32);
      int idx = (ll < cnt) ? csr[rs + base + ll] : fb;
      for (int j = 0; j < cmax; j += 8) {
        uint u0 = xm[(size_t)__shfl(idx, h + j + 0) * 32 + ll];
        uint u1 = xm[(size_t)__shfl(idx, h + j + 1) * 32 + ll];
        uint u2 = xm[(size_t)__shfl(idx, h + j + 2) * 32 + ll];
        uint u3 = xm[(size_t)__shfl(idx, h + j + 3) * 32 + ll];
        uint u4 = xm[(size_t)__shfl(idx, h + j + 4) * 32 + ll];
        uint u5 = xm[(size_t)__shfl(idx, h + j + 5) * 32 + ll];
        uint u6 = xm[(size_t)__shfl(idx, h + j + 6) * 32 + ll];
        uint u7 = xm[(size_t)__shfl(idx, h + j + 7) * 32 + ll];
        m = pkmaxu16(m, pkmaxu16(pkmaxu16(pkmaxu16(u0, u1), pkmaxu16(u2, u3)),
                                 pkmaxu16(pkmaxu16(u4, u5), pkmaxu16(u6, u7))));
      }
    }
    if (valid) {
      uint lo = m & 0xFFFFu, hi = m >> 16;
      lo = (lo & 0x8000u) ? (lo ^ 0x8000u) : (~lo & 0xFFFFu);
      hi = (hi & 0x8000u) ? (hi ^ 0x8000u) : (~hi & 0xFFFFu);
      agg[(size_t)n * 32 + ll] = (d > 0) ? (lo | (hi << 16)) : 0u;
    }
  }
}

// ---- Aggregation layer 1: h0 >= 0 -> plain v_pk_max_u16, neutral 0 --------

__global__ __launch_bounds__(256) void k_agg1(const uint* __restrict__ h0,
                                              const int* __restrict__ rowst,
                                              const int* __restrict__ deg,
                                              const int* __restrict__ csr,
                                              uint* __restrict__ agg, int N) {
  int lane = threadIdx.x & 63;
  int wid = (blockIdx.x * 256 + threadIdx.x) >> 6;
  int nw = (gridDim.x * 256) >> 6;
  for (int n = wid; n < N; n += nw) {
    int rs = rowst[n], d = deg[n];
    uint m = 0;
    if (d > 0) {
      int fb = csr[rs];  // duplicate pad: max is idempotent
      for (int base = 0; base < d; base += 64) {
        int cnt = min(d - base, 64);
        int idx = (lane < cnt) ? csr[rs + base + lane] : fb;
        for (int j = 0; j < cnt; j += 8) {
          uint u0 = h0[(size_t)__shfl(idx, j + 0) * 64 + lane];
          uint u1 = h0[(size_t)__shfl(idx, j + 1) * 64 + lane];
          uint u2 = h0[(size_t)__shfl(idx, j + 2) * 64 + lane];
          uint u3 = h0[(size_t)__shfl(idx, j + 3) * 64 + lane];
          uint u4 = h0[(size_t)__shfl(idx, j + 4) * 64 + lane];
          uint u5 = h0[(size_t)__shfl(idx, j + 5) * 64 + lane];
          uint u6 = h0[(size_t)__shfl(idx, j + 6) * 64 + lane];
          uint u7 = h0[(size_t)__shfl(idx, j + 7) * 64 + lane];
          m = pkmaxu16(m, pkmaxu16(pkmaxu16(pkmaxu16(u0, u1), pkmaxu16(u2, u3)),
                                   pkmaxu16(pkmaxu16(u4, u5), pkmaxu16(u6, u7))));
        }
      }
    }
    agg[(size_t)n * 64 + lane] = m;  // m==0 for empty == required semantics
  }
}

// ---- Layer 0: h0 = LNrelu([agg0|x] @ [Wl0|Wr0]^T + bl0) -------------------
// B-fragments read directly from global wB0 (L2-resident, no LDS/sync).

__global__ __launch_bounds__(256) void k_lin0(
    const uint* __restrict__ agg,  // N x 32 uints (bf16 [N][64])
    const uint* __restrict__ xb,   // N x 32 uints
    const uint4* __restrict__ wB,  // 4096 frag entries
    const float* __restrict__ bl, const float* __restrict__ g,
    const float* __restrict__ be, unsigned short* __restrict__ hout, int N) {
  int lane = threadIdx.x & 63, m = lane & 15, q = lane >> 4;
  int w = (blockIdx.x * 256 + threadIdx.x) >> 6;
  int nw = (gridDim.x * 256) >> 6;
  int pairs = (N + 31) / 32;
  float blv[8], gv[8], bev[8];
#pragma unroll
  for (int jt = 0; jt < 8; jt++) {
    blv[jt] = bl[jt * 16 + m];
    gv[jt] = g[jt * 16 + m];
    bev[jt] = be[jt * 16 + m];
  }
  for (int p = w; p < pairs; p += nw) {
    int b0 = p * 32;
    short8 a[2][4];
#pragma unroll
    for (int t = 0; t < 2; t++) {
      int row = b0 + t * 16 + m;
      const uint* r0 = agg + (size_t)row * 32;
      const uint* r1 = xb + (size_t)row * 32;
#pragma unroll
      for (int ks = 0; ks < 4; ks++) {
        const uint* base = (ks < 2) ? r0 : r1;
        a[t][ks] = __builtin_bit_cast(short8, *(const uint4*)(base + (ks & 1) * 16 + q * 4));
      }
    }
    f32x4 acc[2][8];
#pragma unroll
    for (int t = 0; t < 2; t++)
#pragma unroll
      for (int jt = 0; jt < 8; jt++) acc[t][jt] = {0.f, 0.f, 0.f, 0.f};
#pragma unroll
    for (int ks = 0; ks < 8; ks++) {
#pragma unroll
      for (int jt = 0; jt < 8; jt++) {
        short8 b = __builtin_bit_cast(short8, wB[(ks * 8 + jt) * 64 + lane]);
        acc[0][jt] = __builtin_amdgcn_mfma_f32_16x16x32_bf16(a[0][ks & 3], b, acc[0][jt], 0, 0, 0);
        acc[1][jt] = __builtin_amdgcn_mfma_f32_16x16x32_bf16(a[1][ks & 3], b, acc[1][jt], 0, 0, 0);
      }
    }
#pragma unroll
    for (int t = 0; t < 2; t++) {
      float s1[4] = {0.f, 0.f, 0.f, 0.f}, s2[4] = {0.f, 0.f, 0.f, 0.f};
#pragma unroll
      for (int jt = 0; jt < 8; jt++) {
        float bb = blv[jt];
#pragma unroll
        for (int r = 0; r < 4; r++) {
          float v = acc[t][jt][r] + bb;
          s1[r] += v;
          s2[r] += v * v;
        }
      }
#pragma unroll
      for (int off = 1; off < 16; off <<= 1) {
#pragma unroll
        for (int r = 0; r < 4; r++) {
          s1[r] += __shfl_xor(s1[r], off);
          s2[r] += __shfl_xor(s2[r], off);
        }
      }
      float mu[4], rstd[4];
#pragma unroll
      for (int r = 0; r < 4; r++) {
        mu[r] = s1[r] * (1.0f / 128.0f);
        float var = s2[r] * (1.0f / 128.0f) - mu[r] * mu[r];
        rstd[r] = rsqrtf(var + 1e-5f);
      }
      int nodeb = b0 + t * 16 + q * 4;
#pragma unroll
      for (int jt = 0; jt < 8; jt++) {
        float bb = blv[jt];
#pragma unroll
        for (int r = 0; r < 4; r++) {
          int node = nodeb + r;
          if (node < N) {
            float v = acc[t][jt][r] + bb;
            float o = fmaxf((v - mu[r]) * rstd[r] * gv[jt] + bev[jt], 0.0f);
            hout[(size_t)node * 128 + jt * 16 + m] = f2bf(o);
          }
        }
      }
    }
  }
}

// ---- Layer 1: h1 = LNrelu([agg1|h0] @ [Wl1|Wr1]^T + bl1), in-place --------

__global__ __launch_bounds__(256) void k_lin1(
    uint* agg,                     // N x 64 uints; becomes h1 (bf16 [N][128])
    const uint* __restrict__ h0,   // N x 64 uints
    const uint4* __restrict__ wB,  // 4096 frag entries
    const float* __restrict__ bl, const float* __restrict__ g,
    const float* __restrict__ be, int N) {
  int lane = threadIdx.x & 63, m = lane & 15, q = lane >> 4;
  int w = (blockIdx.x * 256 + threadIdx.x) >> 6;
  int nw = (gridDim.x * 256) >> 6;
  int pairs = (N + 31) / 32;
  float blv[8], gv[8], bev[8];
#pragma unroll
  for (int jt = 0; jt < 8; jt++) {
    blv[jt] = bl[jt * 16 + m];
    gv[jt] = g[jt * 16 + m];
    bev[jt] = be[jt * 16 + m];
  }
  unsigned short* hout = (unsigned short*)agg;
  for (int p = w; p < pairs; p += nw) {
    int b0 = p * 32;
    short8 a[2][8];
#pragma unroll
    for (int t = 0; t < 2; t++) {
      int row = b0 + t * 16 + m;
      const uint* r0 = agg + (size_t)row * 64;
      const uint* r1 = h0 + (size_t)row * 64;
#pragma unroll
      for (int ks = 0; ks < 8; ks++) {
        const uint* base = (ks < 4) ? r0 : r1;
        a[t][ks] = __builtin_bit_cast(short8, *(const uint4*)(base + (ks & 3) * 16 + q * 4));
      }
    }
    f32x4 acc[2][8];
#pragma unroll
    for (int t = 0; t < 2; t++)
#pragma unroll
      for (int jt = 0; jt < 8; jt++) acc[t][jt] = {0.f, 0.f, 0.f, 0.f};
#pragma unroll
    for (int ks = 0; ks < 8; ks++) {
#pragma unroll
      for (int jt = 0; jt < 8; jt++) {
        short8 b = __builtin_bit_cast(short8, wB[(ks * 8 + jt) * 64 + lane]);
        acc[0][jt] = __builtin_amdgcn_mfma_f32_16x16x32_bf16(a[0][ks], b, acc[0][jt], 0, 0, 0);
        acc[1][jt] = __builtin_amdgcn_mfma_f32_16x16x32_bf16(a[1][ks], b, acc[1][jt], 0, 0, 0);
      }
    }
#pragma unroll
    for (int t = 0; t < 2; t++) {
      float s1[4] = {0.f, 0.f, 0.f, 0.f}, s2[4] = {0.f, 0.f, 0.f, 0.f};
#pragma unroll
      for (int jt = 0; jt < 8; jt++) {
        float bb = blv[jt];
#pragma unroll
        for (int r = 0; r < 4; r++) {
          float v = acc[t][jt][r] + bb;
          s1[r] += v;
          s2[r] += v * v;
        }
      }
#pragma unroll
      for (int off = 1; off < 16; off <<= 1) {
#pragma unroll
        for (int r = 0; r < 4; r++) {
          s1[r] += __shfl_xor(s1[r], off);
          s2[r] += __shfl_xor(s2[r], off);
        }
      }
      float mu[4], rstd[4];
#pragma unroll
      for (int r = 0; r < 4; r++) {
        mu[r] = s1[r] * (1.0f / 128.0f);
        float var = s2[r] * (1.0f / 128.0f) - mu[r] * mu[r];
        rstd[r] = rsqrtf(var + 1e-5f);
      }
      int nodeb = b0 + t * 16 + q * 4;
#pragma unroll
      for (int jt = 0; jt < 8; jt++) {
        float bb = blv[jt];
#pragma unroll
        for (int r = 0; r < 4; r++) {
          int node = nodeb + r;
          if (node < N) {
            float v = acc[t][jt][r] + bb;
            float o = fmaxf((v - mu[r]) * rstd[r] * gv[jt] + bev[jt], 0.0f);
            hout[(size_t)node * 128 + jt * 16 + m] = f2bf(o);
          }
        }
      }
    }
  }
}

// ---- MLP head: out = sigmoid(relu(h1@W1.T+b1) @ W2.T + b2) ----------------

__global__ __launch_bounds__(256) void k_mlp(const uint* __restrict__ h1,
                                             const uint4* __restrict__ wB,
                                             const float* __restrict__ b1,
                                             const float* __restrict__ W2,
                                             const float* __restrict__ b2,
                                             float* __restrict__ out, int N) {
  int lane = threadIdx.x & 63, m = lane & 15, q = lane >> 4;
  int w = (blockIdx.x * 256 + threadIdx.x) >> 6;
  int nw = (gridDim.x * 256) >> 6;
  int tiles = (N + 15) / 16;
  float b1v[4], w2v[4];
#pragma unroll
  for (int jt = 0; jt < 4; jt++) {
    b1v[jt] = b1[jt * 16 + m];
    w2v[jt] = W2[jt * 16 + m];
  }
  float b2v = b2[0];
  for (int tl = w; tl < tiles; tl += nw) {
    int b0 = tl * 16;
    int row = b0 + m;
    const uint* r0 = h1 + (size_t)row * 64;
    short8 a[4];
#pragma unroll
    for (int ks = 0; ks < 4; ks++)
      a[ks] = __builtin_bit_cast(short8, *(const uint4*)(r0 + ks * 16 + q * 4));
    f32x4 acc[4];
#pragma unroll
    for (int jt = 0; jt < 4; jt++) acc[jt] = {0.f, 0.f, 0.f, 0.f};
#pragma unroll
    for (int ks = 0; ks < 4; ks++) {
#pragma unroll
      for (int jt = 0; jt < 4; jt++) {
        short8 b = __builtin_bit_cast(short8, wB[(ks * 4 + jt) * 64 + lane]);
        acc[jt] = __builtin_amdgcn_mfma_f32_16x16x32_bf16(a[ks], b, acc[jt], 0, 0, 0);
      }
    }
    float part[4] = {0.f, 0.f, 0.f, 0.f};
#pragma unroll
    for (int jt = 0; jt < 4; jt++) {
#pragma unroll
      for (int r = 0; r < 4; r++)
        part[r] += fmaxf(acc[jt][r] + b1v[jt], 0.0f) * w2v[jt];
    }
#pragma unroll
    for (int off = 1; off < 16; off <<= 1) {
#pragma unroll
      for (int r = 0; r < 4; r++) part[r] += __shfl_xor(part[r], off);
    }
    if (m == 0) {
#pragma unroll
      for (int r = 0; r < 4; r++) {
        int node = b0 + q * 4 + r;
        if (node < N) out[node] = 1.0f / (1.0f + expf(-(part[r] + b2v)));
      }
    }
  }
}

// ---------------------------------------------------------------------------

extern "C" void kernel_launch(void* const* d_in, const int* in_sizes, int n_in,
                              void* d_out, int out_size, void* d_ws, size_t ws_size,
                              hipStream_t stream) {
  const float* x = (const float*)d_in[0];
  const int* ei = (const int*)d_in[1];
  const float* Wl0 = (const float*)d_in[2];
  const float* bl0 = (const float*)d_in[3];
  const float* Wr0 = (const float*)d_in[4];
  const float* g0 = (const float*)d_in[5];
  const float* be0 = (const float*)d_in[6];
  const float* Wl1 = (const float*)d_in[7];
  const float* bl1 = (const float*)d_in[8];
  const float* Wr1 = (const float*)d_in[9];
  const float* g1 = (const float*)d_in[10];
  const float* be1 = (const float*)d_in[11];
  const float* W1 = (const float*)d_in[12];
  const float* b1 = (const float*)d_in[13];
  const float* W2 = (const float*)d_in[14];
  const float* b2 = (const float*)d_in[15];
  float* out = (float*)d_out;

  const int N = in_sizes[0] / 64;
  const int E = in_sizes[1] / 2;
  const int* src = ei;
  const int* dst = ei + E;
  const int nb = ceil_div(N, 1 << NBSHIFT);

  // Workspace (~58.9 MB peak):
  //   misc + csr (6.4 MB) + regionX (25.6 MB) + h0buf (25.6 MB) + wB (144 KB)
  // h0buf timeline: [bed 12.8 | xm 12.8] -> h0 (k_lin0 onward).
  // regionX timeline: [xb | agg0b] -> agg1 -> h1 (in-place).
  char* ws = (char*)d_ws;
  size_t off = 0;
  auto alloc = [&](size_t bytes) -> void* {
    void* p = ws + off;
    off = (off + bytes + 255) & ~(size_t)255;
    return p;
  };
  int* counts = (int*)alloc((size_t)N * 4);
  int* rowst = (int*)alloc((size_t)N * 4);
  int* gbtot = (int*)alloc(512 * 4);
  int* gbase = (int*)alloc(512 * 4);
  int* gbcur = (int*)alloc(512 * 4);
  int* csr = (int*)alloc((size_t)E * 4);
  uint* regionX = (uint*)alloc((size_t)N * 64 * 4);  // 25.6 MB
  uint* h0buf = (uint*)alloc((size_t)N * 64 * 4);    // 25.6 MB
  uint4* wB0 = (uint4*)alloc(4096 * 16);
  uint4* wB1 = (uint4*)alloc(4096 * 16);
  uint4* wBm = (uint4*)alloc(1024 * 16);

  uint* xb = regionX;                      // N x 32 uints
  uint* agg0b = regionX + (size_t)N * 32;  // N x 32 uints
  uint* agg1 = regionX;                    // N x 64 uints (over dead xb/agg0b)
  int2* bed = (int2*)h0buf;                // E x 8 B = first N*32 uints
  uint* xm = h0buf + (size_t)N * 32;       // monotone u16 x (12.8 MB)

  hipMemsetAsync(gbtot, 0, 512 * 4, stream);

  int pairs = (N + 31) / 32;
  int lingrid = ceil_div(pairs, 4);        // ~1 MFMA tile per wave
  int mlpgrid = ceil_div((N + 15) / 16, 4);

  k_wprep<<<36, 256, 0, stream>>>(Wl0, Wr0, Wl1, Wr1, W1, wB0, wB1, wBm);
  k_prep<<<ceil_div(N * 32, 256), 256, 0, stream>>>(x, xb, xm, N * 32);
  k_bhist<<<ceil_div(E, ACHUNK), 256, 0, stream>>>(dst, gbtot, E);
  k_bscan<<<1, 512, 0, stream>>>(gbtot, gbase, gbcur);
  k_passA<<<ceil_div(E, ACHUNK), 256, 0, stream>>>(src, dst, gbcur, bed, E);
  k_passB<<<nb, 256, 0, stream>>>(bed, gbase, counts, rowst, csr, N, E);

  k_agg0b<<<2048, 256, 0, stream>>>(xm, rowst, counts, csr, agg0b, N);
  k_lin0<<<lingrid, 256, 0, stream>>>(agg0b, xb, wB0, bl0, g0, be0,
                                      (unsigned short*)h0buf, N);
  k_agg1<<<2048, 256, 0, stream>>>(h0buf, rowst, counts, csr, agg1, N);
  k_lin1<<<lingrid, 256, 0, stream>>>(agg1, h0buf, wB1, bl1, g1, be1, N);
  k_mlp<<<mlpgrid, 256, 0, stream>>>(agg1, wBm, b1, W2, b2, out, N);
}